// Round 1
// baseline (52854.230 us; speedup 1.0000x reference)
//
#include <hip/hip_runtime.h>
#include <cstdint>
#include <cstddef>

// Problem constants
#define B_   16
#define T_   2000
#define NIN  512
#define U_   512
#define G4   2048      // 4*U
#define KP   1024      // packed K (real|imag)
#define JP   4096      // packed output cols (real plane | imag plane)
#define M_   32000     // B*T
#define NBLK 16        // scan blocks

typedef __attribute__((ext_vector_type(8))) short bf16x8;
typedef __attribute__((ext_vector_type(4))) float f32x4;

#define MFMA(a, b, c) __builtin_amdgcn_mfma_f32_16x16x32_bf16((a), (b), (c), 0, 0, 0)

__device__ __forceinline__ unsigned short f2bf(float f) {
  unsigned u = __builtin_bit_cast(unsigned, f);
  u = (u + 0x7FFFu + ((u >> 16) & 1u)) >> 16;
  return (unsigned short)u;
}
__device__ __forceinline__ float bf2f(unsigned short h) {
  unsigned u = ((unsigned)h) << 16;
  return __builtin_bit_cast(float, u);
}
__device__ __forceinline__ float sigm(float x) {
  return 1.0f / (1.0f + __expf(-x));
}
__device__ __forceinline__ float tanh_f(float x) {
  float cx = fminf(fmaxf(x, -15.0f), 15.0f);
  float e = __expf(2.0f * cx);
  return (e - 1.0f) / (e + 1.0f);
}

// ---------------------------------------------------------------------------
// Convert x_real/x_imag fp32 [M, 512] -> packed A' bf16 [M, 1024] = [xr | xi]
// One thread handles 8 consecutive k of both halves of one row.
// grid: 8000 x 256  (M*512/8 = 2,048,000 threads)
// ---------------------------------------------------------------------------
__global__ __launch_bounds__(256) void k_convert_x(const float* __restrict__ xr,
                                                   const float* __restrict__ xi,
                                                   unsigned short* __restrict__ Ab) {
  int i = blockIdx.x * 256 + threadIdx.x;
  int m = i >> 6;
  int k0 = (i & 63) << 3;
  if (m >= M_) return;
  const float* pr = xr + (size_t)m * NIN + k0;
  const float* pi = xi + (size_t)m * NIN + k0;
  float4 r0 = *reinterpret_cast<const float4*>(pr);
  float4 r1 = *reinterpret_cast<const float4*>(pr + 4);
  float4 i0 = *reinterpret_cast<const float4*>(pi);
  float4 i1 = *reinterpret_cast<const float4*>(pi + 4);
  uint4 rv, iv;
  rv.x = f2bf(r0.x) | ((unsigned)f2bf(r0.y) << 16);
  rv.y = f2bf(r0.z) | ((unsigned)f2bf(r0.w) << 16);
  rv.z = f2bf(r1.x) | ((unsigned)f2bf(r1.y) << 16);
  rv.w = f2bf(r1.z) | ((unsigned)f2bf(r1.w) << 16);
  iv.x = f2bf(i0.x) | ((unsigned)f2bf(i0.y) << 16);
  iv.y = f2bf(i0.z) | ((unsigned)f2bf(i0.w) << 16);
  iv.z = f2bf(i1.x) | ((unsigned)f2bf(i1.y) << 16);
  iv.w = f2bf(i1.z) | ((unsigned)f2bf(i1.w) << 16);
  *reinterpret_cast<uint4*>(Ab + (size_t)m * KP + k0) = rv;
  *reinterpret_cast<uint4*>(Ab + (size_t)m * KP + 512 + k0) = iv;
}

// ---------------------------------------------------------------------------
// Pack a complex weight [512, 2048] (row-major, real+imag planes) into
// Bt bf16 [4096][1024] row-major (transposed, K-packed):
//   jp = p*2048 + j ;  Bt[jp][k] :
//     p=0 (real out):  k<512 ? Wr[k][j]      : -Wi[k-512][j]
//     p=1 (imag out):  k<512 ? Wi[k][j]      :  Wr[k-512][j]
// grid: 16384 x 256 (4096*1024 threads, one elem each)
// ---------------------------------------------------------------------------
__global__ __launch_bounds__(256) void k_pack_B(const float* __restrict__ Wr,
                                                const float* __restrict__ Wi,
                                                unsigned short* __restrict__ Bt) {
  int i = blockIdx.x * 256 + threadIdx.x;
  if (i >= JP * KP) return;
  int jp = i >> 10;
  int k = i & 1023;
  int p = jp >> 11;
  int j = jp & 2047;
  float v;
  if (k < 512) {
    v = p ? Wi[(size_t)k * G4 + j] : Wr[(size_t)k * G4 + j];
  } else {
    int k2 = k - 512;
    v = p ? Wr[(size_t)k2 * G4 + j] : -Wi[(size_t)k2 * G4 + j];
  }
  Bt[i] = f2bf(v);
}

// ---------------------------------------------------------------------------
// zx GEMM: A'[32000,1024] bf16 @ Bt[4096,1024]^T -> zx bf16 [T][B][2048][2]
// 128x128 tiles, 4 waves in 2x2, each wave 64x64 (4x4 frags of 16x16x32).
// No LDS: direct 16B fragment loads (A' L3-resident, Bt L2-resident).
// grid: (250 m-tiles * 32 n-tiles) x 256
// ---------------------------------------------------------------------------
__global__ __launch_bounds__(256) void k_gemm_zx(const unsigned short* __restrict__ A,
                                                 const unsigned short* __restrict__ Bt,
                                                 unsigned short* __restrict__ zx) {
  int bid = blockIdx.x;
  int nt = bid & 31;
  int mt = bid >> 5;
  int tid = threadIdx.x;
  int lane = tid & 63;
  int wid = tid >> 6;
  int wm = wid >> 1, wn = wid & 1;
  int l15 = lane & 15;
  int kb = (lane >> 4) << 3;
  int rowb = mt * 128 + wm * 64;
  int colb = nt * 128 + wn * 64;

  const unsigned short* ap[4];
  const unsigned short* bp[4];
#pragma unroll
  for (int x = 0; x < 4; ++x) {
    ap[x] = A + (size_t)(rowb + x * 16 + l15) * KP + kb;
    bp[x] = Bt + (size_t)(colb + x * 16 + l15) * KP + kb;
  }

  f32x4 acc[4][4];
#pragma unroll
  for (int mi = 0; mi < 4; ++mi)
#pragma unroll
    for (int ni = 0; ni < 4; ++ni) acc[mi][ni] = (f32x4){0.f, 0.f, 0.f, 0.f};

#pragma unroll 2
  for (int k = 0; k < KP; k += 32) {
    bf16x8 av[4], bv[4];
#pragma unroll
    for (int x = 0; x < 4; ++x) {
      av[x] = *reinterpret_cast<const bf16x8*>(ap[x] + k);
      bv[x] = *reinterpret_cast<const bf16x8*>(bp[x] + k);
    }
#pragma unroll
    for (int mi = 0; mi < 4; ++mi)
#pragma unroll
      for (int ni = 0; ni < 4; ++ni)
        acc[mi][ni] = MFMA(av[mi], bv[ni], acc[mi][ni]);
  }

  // epilogue: D row = (lane>>4)*4 + r, D col = lane&15
  int rq = (lane >> 4) << 2;
#pragma unroll
  for (int mi = 0; mi < 4; ++mi) {
#pragma unroll
    for (int r = 0; r < 4; ++r) {
      int m = rowb + mi * 16 + rq + r;
      int bbv = m / T_;
      int tv = m - bbv * T_;
      size_t rowoff = (size_t)(tv * 16 + bbv) * (G4 * 2);
#pragma unroll
      for (int ni = 0; ni < 4; ++ni) {
        int jp2 = colb + ni * 16 + l15;
        int p = jp2 >> 11;
        int j = jp2 & 2047;
        zx[rowoff + (size_t)j * 2 + p] = f2bf(acc[mi][ni][r]);
      }
    }
  }
}

// ---------------------------------------------------------------------------
// Persistent scan. 16 blocks x 512 threads (8 waves). Block g owns units
// [32g, 32g+32). Wave w: gate = w&3, K-half = w>>2. Per wave 4 frags:
// (p = real/imag output plane) x (f = unit half). h broadcast via global
// double-buffered bf16 buffer hb[2][16][1024] ( [b][hr|hi] packed K layout ),
// custom monotone atomic barrier per step.
// ---------------------------------------------------------------------------
__global__ __launch_bounds__(512) void k_scan(const unsigned short* __restrict__ zx,
                                              const unsigned short* __restrict__ Ub,
                                              const float* __restrict__ brp,
                                              const float* __restrict__ bip,
                                              unsigned short* __restrict__ hb,
                                              float* __restrict__ out,
                                              int* bar) {
  int g = blockIdx.x;
  int tid = threadIdx.x;
  int lane = tid & 63;
  int w = tid >> 6;
  int gate = w & 3;
  int kh = w >> 2;
  int bb = tid >> 5;   // gate-stage batch 0..15
  int uu = tid & 31;   // gate-stage local unit 0..31
  int l15 = lane & 15;
  int kb = (lane >> 4) << 3;

  __shared__ float zp[2][4][2][16][32];  // [khalf][gate][plane][batch][unit]

  const unsigned short* bp00 = Ub + (size_t)(0 * 2048 + gate * 512 + g * 32 + 0 + l15) * KP + kh * 512 + kb;
  const unsigned short* bp01 = Ub + (size_t)(0 * 2048 + gate * 512 + g * 32 + 16 + l15) * KP + kh * 512 + kb;
  const unsigned short* bp10 = Ub + (size_t)(1 * 2048 + gate * 512 + g * 32 + 0 + l15) * KP + kh * 512 + kb;
  const unsigned short* bp11 = Ub + (size_t)(1 * 2048 + gate * 512 + g * 32 + 16 + l15) * KP + kh * 512 + kb;
  const int aoff = l15 * KP + kh * 512 + kb;

  float brg[4], big[4];
#pragma unroll
  for (int q = 0; q < 4; ++q) {
    int j = q * 512 + g * 32 + uu;
    brg[q] = brp[j];
    big[q] = bip[j];
  }

  float cr = 0.f, ci = 0.f;

  for (int t = 0; t < T_; ++t) {
    int par = t & 1;

    // prefetch this step's zx (used after the MFMA phase)
    unsigned zv[4];
    const unsigned short* zt = zx + (size_t)(t * 16 + bb) * (G4 * 2);
#pragma unroll
    for (int q = 0; q < 4; ++q)
      zv[q] = *reinterpret_cast<const unsigned*>(zt + (q * 512 + g * 32 + uu) * 2);

    f32x4 a00 = {0.f, 0.f, 0.f, 0.f};
    f32x4 a01 = {0.f, 0.f, 0.f, 0.f};
    f32x4 a10 = {0.f, 0.f, 0.f, 0.f};
    f32x4 a11 = {0.f, 0.f, 0.f, 0.f};
    const unsigned short* apt = hb + (size_t)par * (B_ * KP) + aoff;
#pragma unroll 4
    for (int k = 0; k < 512; k += 32) {
      bf16x8 av = *reinterpret_cast<const bf16x8*>(apt + k);
      a00 = MFMA(av, *reinterpret_cast<const bf16x8*>(bp00 + k), a00);
      a01 = MFMA(av, *reinterpret_cast<const bf16x8*>(bp01 + k), a01);
      a10 = MFMA(av, *reinterpret_cast<const bf16x8*>(bp10 + k), a10);
      a11 = MFMA(av, *reinterpret_cast<const bf16x8*>(bp11 + k), a11);
    }

    int rq = (lane >> 4) << 2;
#pragma unroll
    for (int r = 0; r < 4; ++r) {
      zp[kh][gate][0][rq + r][l15] = a00[r];
      zp[kh][gate][0][rq + r][16 + l15] = a01[r];
      zp[kh][gate][1][rq + r][l15] = a10[r];
      zp[kh][gate][1][rq + r][16 + l15] = a11[r];
    }
    __syncthreads();

    // gate stage: one thread per (batch bb, unit uu)
    float zr[4], zi[4];
#pragma unroll
    for (int q = 0; q < 4; ++q) {
      zr[q] = zp[0][q][0][bb][uu] + zp[1][q][0][bb][uu] + brg[q] +
              bf2f((unsigned short)(zv[q] & 0xFFFFu));
      zi[q] = zp[0][q][1][bb][uu] + zp[1][q][1][bb][uu] + big[q] +
              bf2f((unsigned short)(zv[q] >> 16));
    }
    float ar = tanh_f(zr[0]), ai = tanh_f(zi[0]);
    float ir = sigm(zr[1]), ii = sigm(zi[1]);
    float fr = sigm(zr[2]), fi = sigm(zi[2]);
    float og_r = sigm(zr[3]), og_i = sigm(zi[3]);
    float ncr = ar * ir - ai * ii + fr * cr - fi * ci;
    float nci = ar * ii + ai * ir + fr * ci + fi * cr;
    cr = ncr;
    ci = nci;
    float tr = tanh_f(cr), ti = tanh_f(ci);
    float hr = og_r * tr - og_i * ti;
    float hi = og_r * ti + og_i * tr;

    int u = g * 32 + uu;
    float2 hv;
    hv.x = hr;
    hv.y = hi;
    *reinterpret_cast<float2*>(out + ((size_t)(bb * T_ + t) * U_ + u) * 2) = hv;

    unsigned short* hw = hb + (size_t)(par ^ 1) * (B_ * KP);
    hw[bb * KP + u] = f2bf(hr);
    hw[bb * KP + 512 + u] = f2bf(hi);

    // grid barrier: release writes, arrive, spin, acquire
    __threadfence();
    __syncthreads();
    if (tid == 0) {
      int prev = __hip_atomic_fetch_add(bar, 1, __ATOMIC_ACQ_REL, __HIP_MEMORY_SCOPE_AGENT);
      if (prev == NBLK * (t + 1) - 1) {
        __hip_atomic_store(bar + 1, t + 1, __ATOMIC_RELEASE, __HIP_MEMORY_SCOPE_AGENT);
      } else {
        while (__hip_atomic_load(bar + 1, __ATOMIC_ACQUIRE, __HIP_MEMORY_SCOPE_AGENT) < t + 1) {
        }
      }
    }
    __syncthreads();
    __threadfence();
  }
}

// ---------------------------------------------------------------------------
extern "C" void kernel_launch(void* const* d_in, const int* in_sizes, int n_in,
                              void* d_out, int out_size, void* d_ws, size_t ws_size,
                              hipStream_t stream) {
  const float* xr = (const float*)d_in[0];
  const float* xi = (const float*)d_in[1];
  const float* Wr = (const float*)d_in[2];
  const float* Wi = (const float*)d_in[3];
  const float* Ur = (const float*)d_in[4];
  const float* Ui = (const float*)d_in[5];
  const float* br = (const float*)d_in[6];
  const float* bi = (const float*)d_in[7];

  const size_t SZ_ZX = (size_t)M_ * G4 * 2 * 2;  // 262,144,000
  const size_t SZ_AB = (size_t)M_ * KP * 2;      //  65,536,000
  const size_t SZ_BT = (size_t)JP * KP * 2;      //   8,388,608
  const size_t SZ_HB = (size_t)2 * B_ * KP * 2;  //      65,536
  const size_t OFF_ZX = 0;
  const size_t OFF_AB = OFF_ZX + SZ_ZX;
  const size_t OFF_BW = OFF_AB + SZ_AB;
  const size_t OFF_BU = OFF_BW + SZ_BT;
  const size_t OFF_HB = OFF_BU + SZ_BT;
  const size_t OFF_BAR = OFF_HB + SZ_HB;
  const size_t NEEDED = OFF_BAR + 256;
  if (ws_size < NEEDED) return;  // insufficient scratch

  char* ws = (char*)d_ws;
  unsigned short* zx = (unsigned short*)(ws + OFF_ZX);
  unsigned short* Ab = (unsigned short*)(ws + OFF_AB);
  unsigned short* BtW = (unsigned short*)(ws + OFF_BW);
  unsigned short* BtU = (unsigned short*)(ws + OFF_BU);
  unsigned short* hb = (unsigned short*)(ws + OFF_HB);
  int* bar = (int*)(ws + OFF_BAR);

  // zero h0 state + barrier counters (contiguous region)
  hipMemsetAsync(ws + OFF_HB, 0, SZ_HB + 256, stream);

  hipLaunchKernelGGL(k_convert_x, dim3(8000), dim3(256), 0, stream, xr, xi, Ab);
  hipLaunchKernelGGL(k_pack_B, dim3(16384), dim3(256), 0, stream, Wr, Wi, BtW);
  hipLaunchKernelGGL(k_pack_B, dim3(16384), dim3(256), 0, stream, Ur, Ui, BtU);
  hipLaunchKernelGGL(k_gemm_zx, dim3(250 * 32), dim3(256), 0, stream, Ab, BtW, zx);
  hipLaunchKernelGGL(k_scan, dim3(NBLK), dim3(512), 0, stream, zx, BtU, br, bi, hb,
                     (float*)d_out, bar);
}

// Round 2
// 20913.777 us; speedup vs baseline: 2.5272x; 2.5272x over previous
//
#include <hip/hip_runtime.h>
#include <cstdint>
#include <cstddef>

// Problem constants
#define B_   16
#define T_   2000
#define NIN  512
#define U_   512
#define G4   2048      // 4*U
#define KP   1024      // packed K (real|imag)
#define JP   4096      // packed output cols (real plane | imag plane)
#define M_   32000     // B*T
#define NBLK 64        // scan blocks (one per CU, 8 units each)

typedef __attribute__((ext_vector_type(8))) short bf16x8;
typedef __attribute__((ext_vector_type(4))) float f32x4;

#define MFMA(a, b, c) __builtin_amdgcn_mfma_f32_16x16x32_bf16((a), (b), (c), 0, 0, 0)

__device__ __forceinline__ unsigned short f2bf(float f) {
  unsigned u = __builtin_bit_cast(unsigned, f);
  u = (u + 0x7FFFu + ((u >> 16) & 1u)) >> 16;
  return (unsigned short)u;
}
__device__ __forceinline__ float bf2f(unsigned short h) {
  unsigned u = ((unsigned)h) << 16;
  return __builtin_bit_cast(float, u);
}
__device__ __forceinline__ float sigm(float x) {
  return 1.0f / (1.0f + __expf(-x));
}
__device__ __forceinline__ float tanh_f(float x) {
  float cx = fminf(fmaxf(x, -15.0f), 15.0f);
  float e = __expf(2.0f * cx);
  return (e - 1.0f) / (e + 1.0f);
}

// ---------------------------------------------------------------------------
// Convert x_real/x_imag fp32 [M, 512] -> packed A' bf16 [M, 1024] = [xr | xi]
// ---------------------------------------------------------------------------
__global__ __launch_bounds__(256) void k_convert_x(const float* __restrict__ xr,
                                                   const float* __restrict__ xi,
                                                   unsigned short* __restrict__ Ab) {
  int i = blockIdx.x * 256 + threadIdx.x;
  int m = i >> 6;
  int k0 = (i & 63) << 3;
  if (m >= M_) return;
  const float* pr = xr + (size_t)m * NIN + k0;
  const float* pi = xi + (size_t)m * NIN + k0;
  float4 r0 = *reinterpret_cast<const float4*>(pr);
  float4 r1 = *reinterpret_cast<const float4*>(pr + 4);
  float4 i0 = *reinterpret_cast<const float4*>(pi);
  float4 i1 = *reinterpret_cast<const float4*>(pi + 4);
  uint4 rv, iv;
  rv.x = f2bf(r0.x) | ((unsigned)f2bf(r0.y) << 16);
  rv.y = f2bf(r0.z) | ((unsigned)f2bf(r0.w) << 16);
  rv.z = f2bf(r1.x) | ((unsigned)f2bf(r1.y) << 16);
  rv.w = f2bf(r1.z) | ((unsigned)f2bf(r1.w) << 16);
  iv.x = f2bf(i0.x) | ((unsigned)f2bf(i0.y) << 16);
  iv.y = f2bf(i0.z) | ((unsigned)f2bf(i0.w) << 16);
  iv.z = f2bf(i1.x) | ((unsigned)f2bf(i1.y) << 16);
  iv.w = f2bf(i1.z) | ((unsigned)f2bf(i1.w) << 16);
  *reinterpret_cast<uint4*>(Ab + (size_t)m * KP + k0) = rv;
  *reinterpret_cast<uint4*>(Ab + (size_t)m * KP + 512 + k0) = iv;
}

// ---------------------------------------------------------------------------
// Pack complex weight [512, 2048] (real+imag planes) into Bt bf16 [4096][1024]
//   jp = p*2048 + j ;  Bt[jp][k]:
//     p=0: k<512 ? Wr[k][j] : -Wi[k-512][j]
//     p=1: k<512 ? Wi[k][j] :  Wr[k-512][j]
// ---------------------------------------------------------------------------
__global__ __launch_bounds__(256) void k_pack_B(const float* __restrict__ Wr,
                                                const float* __restrict__ Wi,
                                                unsigned short* __restrict__ Bt) {
  int i = blockIdx.x * 256 + threadIdx.x;
  if (i >= JP * KP) return;
  int jp = i >> 10;
  int k = i & 1023;
  int p = jp >> 11;
  int j = jp & 2047;
  float v;
  if (k < 512) {
    v = p ? Wi[(size_t)k * G4 + j] : Wr[(size_t)k * G4 + j];
  } else {
    int k2 = k - 512;
    v = p ? Wr[(size_t)k2 * G4 + j] : -Wi[(size_t)k2 * G4 + j];
  }
  Bt[i] = f2bf(v);
}

// ---------------------------------------------------------------------------
// zx GEMM: A'[32000,1024] bf16 @ Bt[4096,1024]^T -> zx bf16 [T][B][2048][2]
// ---------------------------------------------------------------------------
__global__ __launch_bounds__(256) void k_gemm_zx(const unsigned short* __restrict__ A,
                                                 const unsigned short* __restrict__ Bt,
                                                 unsigned short* __restrict__ zx) {
  int bid = blockIdx.x;
  int nt = bid & 31;
  int mt = bid >> 5;
  int tid = threadIdx.x;
  int lane = tid & 63;
  int wid = tid >> 6;
  int wm = wid >> 1, wn = wid & 1;
  int l15 = lane & 15;
  int kb = (lane >> 4) << 3;
  int rowb = mt * 128 + wm * 64;
  int colb = nt * 128 + wn * 64;

  const unsigned short* ap[4];
  const unsigned short* bp[4];
#pragma unroll
  for (int x = 0; x < 4; ++x) {
    ap[x] = A + (size_t)(rowb + x * 16 + l15) * KP + kb;
    bp[x] = Bt + (size_t)(colb + x * 16 + l15) * KP + kb;
  }

  f32x4 acc[4][4];
#pragma unroll
  for (int mi = 0; mi < 4; ++mi)
#pragma unroll
    for (int ni = 0; ni < 4; ++ni) acc[mi][ni] = (f32x4){0.f, 0.f, 0.f, 0.f};

#pragma unroll 2
  for (int k = 0; k < KP; k += 32) {
    bf16x8 av[4], bv[4];
#pragma unroll
    for (int x = 0; x < 4; ++x) {
      av[x] = *reinterpret_cast<const bf16x8*>(ap[x] + k);
      bv[x] = *reinterpret_cast<const bf16x8*>(bp[x] + k);
    }
#pragma unroll
    for (int mi = 0; mi < 4; ++mi)
#pragma unroll
      for (int ni = 0; ni < 4; ++ni)
        acc[mi][ni] = MFMA(av[mi], bv[ni], acc[mi][ni]);
  }

  int rq = (lane >> 4) << 2;
#pragma unroll
  for (int mi = 0; mi < 4; ++mi) {
#pragma unroll
    for (int r = 0; r < 4; ++r) {
      int m = rowb + mi * 16 + rq + r;
      int bbv = m / T_;
      int tv = m - bbv * T_;
      size_t rowoff = (size_t)(tv * 16 + bbv) * (G4 * 2);
#pragma unroll
      for (int ni = 0; ni < 4; ++ni) {
        int jp2 = colb + ni * 16 + l15;
        int p = jp2 >> 11;
        int j = jp2 & 2047;
        zx[rowoff + (size_t)j * 2 + p] = f2bf(acc[mi][ni][r]);
      }
    }
  }
}

// ---------------------------------------------------------------------------
// Persistent scan v2. 64 blocks x 256 threads (4 waves), 1 block/CU.
// Block g owns units [8g, 8g+8) -> 64 packed jp-rows, U-slice 128KB held in
// REGISTERS (128 VGPR/thread) so per-step agent fences can't evict it.
// Per step: stage 32KB h (global->LDS, XOR-swizzled), 4 waves x 32 MFMA
// (B-operand from regs), gate stage on threads 0..127, publish 512B h,
// flag-array barrier (relaxed polls + one acquire fence).
// ---------------------------------------------------------------------------
__global__ __launch_bounds__(256, 1) void k_scan(const unsigned short* __restrict__ zx,
                                                 const unsigned short* __restrict__ Ub,
                                                 const float* __restrict__ brp,
                                                 const float* __restrict__ bip,
                                                 unsigned short* __restrict__ hb,
                                                 float* __restrict__ out,
                                                 int* __restrict__ flags) {
  const int g = blockIdx.x;
  const int tid = threadIdx.x;
  const int lane = tid & 63;
  const int w = tid >> 6;
  const int l15 = lane & 15;

  __shared__ uint4 lds_h4[2048];  // 32 KB staged h (swizzled)
  __shared__ float zp[16][66];    // [batch][row-idx], padded
  char* lds_h = (char*)lds_h4;

  // --- U fragments in registers: wave w owns block-rows [w*16, w*16+16) ---
  // row idx -> (plane p, gate, local unit): idx = p*32 + gate*8 + uu
  const int idx = w * 16 + l15;
  const int p_ = idx >> 5, gate_ = (idx >> 3) & 3, uu_ = idx & 7;
  const size_t jprow = (size_t)(p_ * 2048 + gate_ * 512 + g * 8 + uu_);
  const unsigned short* uptr = Ub + jprow * KP + ((lane >> 4) << 3);
  bf16x8 uf[32];
#pragma unroll
  for (int kk = 0; kk < 32; ++kk)
    uf[kk] = *reinterpret_cast<const bf16x8*>(uptr + kk * 32);

  // --- gate-stage mapping (threads 0..127): one (batch, unit) pair each ---
  const int gb = tid >> 3;  // batch
  const int gu = tid & 7;   // local unit
  const int u = g * 8 + gu; // global unit
  float brg[4], big[4];
  if (tid < 128) {
#pragma unroll
    for (int q = 0; q < 4; ++q) {
      brg[q] = brp[q * 512 + u];
      big[q] = bip[q * 512 + u];
    }
  }
  float cr = 0.f, ci = 0.f;

  // --- A-frag LDS addressing (swizzled) ---
  const int hrow = l15 * 2048;
  const int klo = (lane >> 4) << 4;
  const int swz = (l15 & 7) << 4;

  for (int t = 0; t < T_; ++t) {
    const int par = t & 1;

    // ---- stage h[par] global -> LDS (XOR swizzle on 16B chunks) ----
    const unsigned short* hsrc = hb + (size_t)par * (B_ * KP);
    uint4 sv[8];
#pragma unroll
    for (int c = 0; c < 8; ++c)
      sv[c] = *reinterpret_cast<const uint4*>(hsrc + c * 2048 + tid * 8);

    // zx prefetch for the gate stage (issued early to hide HBM latency)
    unsigned zv[4];
    if (tid < 128) {
      const unsigned short* zt = zx + (size_t)(t * 16 + gb) * (G4 * 2);
#pragma unroll
      for (int q = 0; q < 4; ++q)
        zv[q] = *reinterpret_cast<const unsigned*>(zt + (q * 512 + u) * 2);
    }

#pragma unroll
    for (int c = 0; c < 8; ++c) {
      int e = c * 2048 + tid * 8;   // linear element in [16][1024]
      int b = e >> 10;
      int k2 = (e & 1023) * 2;      // byte offset in row
      *reinterpret_cast<uint4*>(lds_h + b * 2048 + (k2 ^ ((b & 7) << 4))) = sv[c];
    }
    __syncthreads();

    // ---- MFMA: z[16 batches x 16 rows], two accs to break dep chain ----
    f32x4 acc0 = {0.f, 0.f, 0.f, 0.f};
    f32x4 acc1 = {0.f, 0.f, 0.f, 0.f};
#pragma unroll
    for (int kk = 0; kk < 32; kk += 2) {
      bf16x8 a0 = *reinterpret_cast<const bf16x8*>(
          lds_h + hrow + (((kk << 6) | klo) ^ swz));
      bf16x8 a1 = *reinterpret_cast<const bf16x8*>(
          lds_h + hrow + ((((kk + 1) << 6) | klo) ^ swz));
      acc0 = MFMA(a0, uf[kk], acc0);
      acc1 = MFMA(a1, uf[kk + 1], acc1);
    }
    const int rq = (lane >> 4) << 2;
#pragma unroll
    for (int r = 0; r < 4; ++r)
      zp[rq + r][idx] = acc0[r] + acc1[r];
    __syncthreads();

    // ---- gate stage ----
    if (tid < 128) {
      float zr[4], zi[4];
#pragma unroll
      for (int q = 0; q < 4; ++q) {
        zr[q] = zp[gb][q * 8 + gu] + brg[q] +
                bf2f((unsigned short)(zv[q] & 0xFFFFu));
        zi[q] = zp[gb][32 + q * 8 + gu] + big[q] +
                bf2f((unsigned short)(zv[q] >> 16));
      }
      float ar = tanh_f(zr[0]), ai = tanh_f(zi[0]);
      float ir = sigm(zr[1]), ii = sigm(zi[1]);
      float fr = sigm(zr[2]), fi = sigm(zi[2]);
      float og_r = sigm(zr[3]), og_i = sigm(zi[3]);
      float ncr = ar * ir - ai * ii + fr * cr - fi * ci;
      float nci = ar * ii + ai * ir + fr * ci + fi * cr;
      cr = ncr;
      ci = nci;
      float tr = tanh_f(cr), ti = tanh_f(ci);
      float hr = og_r * tr - og_i * ti;
      float hi = og_r * ti + og_i * tr;

      float2 hv;
      hv.x = hr;
      hv.y = hi;
      *reinterpret_cast<float2*>(out + ((size_t)(gb * T_ + t) * U_ + u) * 2) = hv;

      unsigned short* hw = hb + (size_t)(par ^ 1) * (B_ * KP) + gb * KP;
      hw[u] = f2bf(hr);
      hw[512 + u] = f2bf(hi);
    }

    // ---- publish + flag barrier ----
    __builtin_amdgcn_fence(__ATOMIC_RELEASE, "agent");
    __syncthreads();
    if (tid == 0)
      __hip_atomic_store(&flags[g], t + 1, __ATOMIC_RELEASE,
                         __HIP_MEMORY_SCOPE_AGENT);
    if (w == 0) {
      const int target = t + 1;
      while (true) {
        int v = __hip_atomic_load(&flags[lane], __ATOMIC_RELAXED,
                                  __HIP_MEMORY_SCOPE_AGENT);
        if (__all(v >= target)) break;
        __builtin_amdgcn_s_sleep(1);
      }
    }
    __syncthreads();
    __builtin_amdgcn_fence(__ATOMIC_ACQUIRE, "agent");
  }
}

// ---------------------------------------------------------------------------
extern "C" void kernel_launch(void* const* d_in, const int* in_sizes, int n_in,
                              void* d_out, int out_size, void* d_ws, size_t ws_size,
                              hipStream_t stream) {
  const float* xr = (const float*)d_in[0];
  const float* xi = (const float*)d_in[1];
  const float* Wr = (const float*)d_in[2];
  const float* Wi = (const float*)d_in[3];
  const float* Ur = (const float*)d_in[4];
  const float* Ui = (const float*)d_in[5];
  const float* br = (const float*)d_in[6];
  const float* bi = (const float*)d_in[7];

  const size_t SZ_ZX = (size_t)M_ * G4 * 2 * 2;  // 262,144,000
  const size_t SZ_AB = (size_t)M_ * KP * 2;      //  65,536,000
  const size_t SZ_BT = (size_t)JP * KP * 2;      //   8,388,608
  const size_t SZ_HB = (size_t)2 * B_ * KP * 2;  //      65,536
  const size_t OFF_ZX = 0;
  const size_t OFF_AB = OFF_ZX + SZ_ZX;
  const size_t OFF_BW = OFF_AB + SZ_AB;
  const size_t OFF_BU = OFF_BW + SZ_BT;
  const size_t OFF_HB = OFF_BU + SZ_BT;
  const size_t OFF_FLAGS = OFF_HB + SZ_HB;
  const size_t NEEDED = OFF_FLAGS + 256;
  if (ws_size < NEEDED) return;  // insufficient scratch

  char* ws = (char*)d_ws;
  unsigned short* zx = (unsigned short*)(ws + OFF_ZX);
  unsigned short* Ab = (unsigned short*)(ws + OFF_AB);
  unsigned short* BtW = (unsigned short*)(ws + OFF_BW);
  unsigned short* BtU = (unsigned short*)(ws + OFF_BU);
  unsigned short* hb = (unsigned short*)(ws + OFF_HB);
  int* flags = (int*)(ws + OFF_FLAGS);

  // zero h0 state + flags (contiguous region), every launch (graph replay!)
  hipMemsetAsync(ws + OFF_HB, 0, SZ_HB + 256, stream);

  hipLaunchKernelGGL(k_convert_x, dim3(8000), dim3(256), 0, stream, xr, xi, Ab);
  hipLaunchKernelGGL(k_pack_B, dim3(16384), dim3(256), 0, stream, Wr, Wi, BtW);
  hipLaunchKernelGGL(k_pack_B, dim3(16384), dim3(256), 0, stream, Ur, Ui, BtU);
  hipLaunchKernelGGL(k_gemm_zx, dim3(250 * 32), dim3(256), 0, stream, Ab, BtW, zx);
  hipLaunchKernelGGL(k_scan, dim3(NBLK), dim3(256), 0, stream, zx, BtU, br, bi, hb,
                     (float*)d_out, flags);
}

// Round 3
// 10538.683 us; speedup vs baseline: 5.0153x; 1.9845x over previous
//
#include <hip/hip_runtime.h>
#include <cstdint>
#include <cstddef>

// Problem constants
#define B_   16
#define T_   2000
#define NIN  512
#define U_   512
#define G4   2048      // 4*U
#define KP   1024      // packed K (real|imag)
#define JP   4096      // packed output cols (real plane | imag plane)
#define M_   32000     // B*T
#define NBLK 64        // scan blocks (one per CU, 8 units each)

typedef __attribute__((ext_vector_type(8))) short bf16x8;
typedef __attribute__((ext_vector_type(4))) float f32x4;

#define MFMA(a, b, c) __builtin_amdgcn_mfma_f32_16x16x32_bf16((a), (b), (c), 0, 0, 0)

__device__ __forceinline__ unsigned short f2bf(float f) {
  unsigned u = __builtin_bit_cast(unsigned, f);
  u = (u + 0x7FFFu + ((u >> 16) & 1u)) >> 16;
  return (unsigned short)u;
}
__device__ __forceinline__ float bf2f(unsigned short h) {
  unsigned u = ((unsigned)h) << 16;
  return __builtin_bit_cast(float, u);
}
__device__ __forceinline__ float sigm(float x) {
  return 1.0f / (1.0f + __expf(-x));
}
__device__ __forceinline__ float tanh_f(float x) {
  float cx = fminf(fmaxf(x, -15.0f), 15.0f);
  float e = __expf(2.0f * cx);
  return (e - 1.0f) / (e + 1.0f);
}

// --- coherence-point (L3) accessors: bypass L1/L2 via sc0 sc1, no cache
// maintenance ops needed for cross-XCD visibility ---
__device__ __forceinline__ uint4 ld_coh16(const void* p) {
  uint4 r;
  asm volatile("global_load_dwordx4 %0, %1, off sc0 sc1"
               : "=v"(r) : "v"(p) : "memory");
  return r;
}
__device__ __forceinline__ int ld_coh4(const void* p) {
  int r;
  asm volatile("global_load_dword %0, %1, off sc0 sc1"
               : "=v"(r) : "v"(p) : "memory");
  return r;
}
__device__ __forceinline__ void st_coh2(void* p, unsigned v) {
  asm volatile("global_store_short %0, %1, off sc0 sc1"
               :: "v"(p), "v"(v) : "memory");
}
__device__ __forceinline__ void st_coh4(void* p, int v) {
  asm volatile("global_store_dword %0, %1, off sc0 sc1"
               :: "v"(p), "v"(v) : "memory");
}
__device__ __forceinline__ void wait_vm0() {
  asm volatile("s_waitcnt vmcnt(0)" ::: "memory");
}

// ---------------------------------------------------------------------------
// Convert x_real/x_imag fp32 [M, 512] -> packed A' bf16 [M, 1024] = [xr | xi]
// ---------------------------------------------------------------------------
__global__ __launch_bounds__(256) void k_convert_x(const float* __restrict__ xr,
                                                   const float* __restrict__ xi,
                                                   unsigned short* __restrict__ Ab) {
  int i = blockIdx.x * 256 + threadIdx.x;
  int m = i >> 6;
  int k0 = (i & 63) << 3;
  if (m >= M_) return;
  const float* pr = xr + (size_t)m * NIN + k0;
  const float* pi = xi + (size_t)m * NIN + k0;
  float4 r0 = *reinterpret_cast<const float4*>(pr);
  float4 r1 = *reinterpret_cast<const float4*>(pr + 4);
  float4 i0 = *reinterpret_cast<const float4*>(pi);
  float4 i1 = *reinterpret_cast<const float4*>(pi + 4);
  uint4 rv, iv;
  rv.x = f2bf(r0.x) | ((unsigned)f2bf(r0.y) << 16);
  rv.y = f2bf(r0.z) | ((unsigned)f2bf(r0.w) << 16);
  rv.z = f2bf(r1.x) | ((unsigned)f2bf(r1.y) << 16);
  rv.w = f2bf(r1.z) | ((unsigned)f2bf(r1.w) << 16);
  iv.x = f2bf(i0.x) | ((unsigned)f2bf(i0.y) << 16);
  iv.y = f2bf(i0.z) | ((unsigned)f2bf(i0.w) << 16);
  iv.z = f2bf(i1.x) | ((unsigned)f2bf(i1.y) << 16);
  iv.w = f2bf(i1.z) | ((unsigned)f2bf(i1.w) << 16);
  *reinterpret_cast<uint4*>(Ab + (size_t)m * KP + k0) = rv;
  *reinterpret_cast<uint4*>(Ab + (size_t)m * KP + 512 + k0) = iv;
}

// ---------------------------------------------------------------------------
// Pack complex weight [512, 2048] (real+imag planes) into Bt bf16 [4096][1024]
//   jp = p*2048 + j ;  Bt[jp][k]:
//     p=0: k<512 ? Wr[k][j] : -Wi[k-512][j]
//     p=1: k<512 ? Wi[k][j] :  Wr[k-512][j]
// ---------------------------------------------------------------------------
__global__ __launch_bounds__(256) void k_pack_B(const float* __restrict__ Wr,
                                                const float* __restrict__ Wi,
                                                unsigned short* __restrict__ Bt) {
  int i = blockIdx.x * 256 + threadIdx.x;
  if (i >= JP * KP) return;
  int jp = i >> 10;
  int k = i & 1023;
  int p = jp >> 11;
  int j = jp & 2047;
  float v;
  if (k < 512) {
    v = p ? Wi[(size_t)k * G4 + j] : Wr[(size_t)k * G4 + j];
  } else {
    int k2 = k - 512;
    v = p ? Wr[(size_t)k2 * G4 + j] : -Wi[(size_t)k2 * G4 + j];
  }
  Bt[i] = f2bf(v);
}

// ---------------------------------------------------------------------------
// zx GEMM: A'[32000,1024] bf16 @ Bt[4096,1024]^T -> zx bf16 [T][B][2048][2]
// ---------------------------------------------------------------------------
__global__ __launch_bounds__(256) void k_gemm_zx(const unsigned short* __restrict__ A,
                                                 const unsigned short* __restrict__ Bt,
                                                 unsigned short* __restrict__ zx) {
  int bid = blockIdx.x;
  int nt = bid & 31;
  int mt = bid >> 5;
  int tid = threadIdx.x;
  int lane = tid & 63;
  int wid = tid >> 6;
  int wm = wid >> 1, wn = wid & 1;
  int l15 = lane & 15;
  int kb = (lane >> 4) << 3;
  int rowb = mt * 128 + wm * 64;
  int colb = nt * 128 + wn * 64;

  const unsigned short* ap[4];
  const unsigned short* bp[4];
#pragma unroll
  for (int x = 0; x < 4; ++x) {
    ap[x] = A + (size_t)(rowb + x * 16 + l15) * KP + kb;
    bp[x] = Bt + (size_t)(colb + x * 16 + l15) * KP + kb;
  }

  f32x4 acc[4][4];
#pragma unroll
  for (int mi = 0; mi < 4; ++mi)
#pragma unroll
    for (int ni = 0; ni < 4; ++ni) acc[mi][ni] = (f32x4){0.f, 0.f, 0.f, 0.f};

#pragma unroll 2
  for (int k = 0; k < KP; k += 32) {
    bf16x8 av[4], bv[4];
#pragma unroll
    for (int x = 0; x < 4; ++x) {
      av[x] = *reinterpret_cast<const bf16x8*>(ap[x] + k);
      bv[x] = *reinterpret_cast<const bf16x8*>(bp[x] + k);
    }
#pragma unroll
    for (int mi = 0; mi < 4; ++mi)
#pragma unroll
      for (int ni = 0; ni < 4; ++ni)
        acc[mi][ni] = MFMA(av[mi], bv[ni], acc[mi][ni]);
  }

  int rq = (lane >> 4) << 2;
#pragma unroll
  for (int mi = 0; mi < 4; ++mi) {
#pragma unroll
    for (int r = 0; r < 4; ++r) {
      int m = rowb + mi * 16 + rq + r;
      int bbv = m / T_;
      int tv = m - bbv * T_;
      size_t rowoff = (size_t)(tv * 16 + bbv) * (G4 * 2);
#pragma unroll
      for (int ni = 0; ni < 4; ++ni) {
        int jp2 = colb + ni * 16 + l15;
        int p = jp2 >> 11;
        int j = jp2 & 2047;
        zx[rowoff + (size_t)j * 2 + p] = f2bf(acc[mi][ni][r]);
      }
    }
  }
}

// ---------------------------------------------------------------------------
// Persistent scan v3. 64 blocks x 256 threads (4 waves), 1 block/CU.
// Block g owns units [8g, 8g+8) -> 64 packed jp-rows; U-slice 128KB PINNED in
// registers via asm (compiler can no longer rematerialize the loads).
// Cross-block h/flag traffic uses sc0-sc1 (coherence-point) loads/stores ->
// NO per-step cache invalidation; zx/Ub/out stay warm in L1/L2.
// ---------------------------------------------------------------------------
__global__ __launch_bounds__(256, 1) void k_scan(const unsigned short* __restrict__ zx,
                                                 const unsigned short* __restrict__ Ub,
                                                 const float* __restrict__ brp,
                                                 const float* __restrict__ bip,
                                                 unsigned short* __restrict__ hb,
                                                 float* __restrict__ out,
                                                 int* __restrict__ flags) {
  const int g = blockIdx.x;
  const int tid = threadIdx.x;
  const int lane = tid & 63;
  const int w = tid >> 6;
  const int l15 = lane & 15;

  __shared__ uint4 lds_h4[2048];  // 32 KB staged h (swizzled)
  __shared__ float zp[16][66];    // [batch][row-idx], padded
  char* lds_h = (char*)lds_h4;

  // --- U fragments in registers: wave w owns block-rows [w*16, w*16+16) ---
  // row idx -> (plane p, gate, local unit): idx = p*32 + gate*8 + uu
  const int idx = w * 16 + l15;
  const int p_ = idx >> 5, gate_ = (idx >> 3) & 3, uu_ = idx & 7;
  const size_t jprow = (size_t)(p_ * 2048 + gate_ * 512 + g * 8 + uu_);
  const unsigned short* uptr = Ub + jprow * KP + ((lane >> 4) << 3);
  bf16x8 uf[32];
#pragma unroll
  for (int kk = 0; kk < 32; ++kk)
    uf[kk] = *reinterpret_cast<const bf16x8*>(uptr + kk * 32);
  // Pin: make each fragment an opaque asm-produced value so the compiler
  // cannot sink the loads into the T-loop (round-2 failure: VGPR_Count=124).
#pragma unroll
  for (int kk = 0; kk < 32; ++kk)
    asm volatile("" : "+v"(uf[kk]));

  // --- gate-stage mapping (threads 0..127): one (batch, unit) pair each ---
  const int gb = tid >> 3;  // batch
  const int gu = tid & 7;   // local unit
  const int u = g * 8 + gu; // global unit
  float brg[4], big[4];
  if (tid < 128) {
#pragma unroll
    for (int q = 0; q < 4; ++q) {
      brg[q] = brp[q * 512 + u];
      big[q] = bip[q * 512 + u];
    }
  }
  float cr = 0.f, ci = 0.f;

  // --- A-frag LDS addressing (swizzled) ---
  const int hrow = l15 * 2048;
  const int klo = (lane >> 4) << 4;
  const int swz = (l15 & 7) << 4;

  for (int t = 0; t < T_; ++t) {
    const int par = t & 1;

    // ---- stage h[par] global(L3) -> LDS, coherent loads ----
    const unsigned short* hsrc = hb + (size_t)par * (B_ * KP);
    uint4 sv[8];
#pragma unroll
    for (int c = 0; c < 8; ++c)
      sv[c] = ld_coh16(hsrc + c * 2048 + tid * 8);

    // zx prefetch for the gate stage (plain cached loads, static data)
    unsigned zv[4];
    if (tid < 128) {
      const unsigned short* zt = zx + (size_t)(t * 16 + gb) * (G4 * 2);
#pragma unroll
      for (int q = 0; q < 4; ++q)
        zv[q] = *reinterpret_cast<const unsigned*>(zt + (q * 512 + u) * 2);
    }
    wait_vm0();

#pragma unroll
    for (int c = 0; c < 8; ++c) {
      int e = c * 2048 + tid * 8;   // linear element in [16][1024]
      int b = e >> 10;
      int k2 = (e & 1023) * 2;      // byte offset in row
      *reinterpret_cast<uint4*>(lds_h + b * 2048 + (k2 ^ ((b & 7) << 4))) = sv[c];
    }
    __syncthreads();

    // ---- MFMA: z[16 batches x 16 rows], two accs to break dep chain ----
    f32x4 acc0 = {0.f, 0.f, 0.f, 0.f};
    f32x4 acc1 = {0.f, 0.f, 0.f, 0.f};
#pragma unroll
    for (int kk = 0; kk < 32; kk += 2) {
      bf16x8 a0 = *reinterpret_cast<const bf16x8*>(
          lds_h + hrow + (((kk << 6) | klo) ^ swz));
      bf16x8 a1 = *reinterpret_cast<const bf16x8*>(
          lds_h + hrow + ((((kk + 1) << 6) | klo) ^ swz));
      acc0 = MFMA(a0, uf[kk], acc0);
      acc1 = MFMA(a1, uf[kk + 1], acc1);
    }
    const int rq = (lane >> 4) << 2;
#pragma unroll
    for (int r = 0; r < 4; ++r)
      zp[rq + r][idx] = acc0[r] + acc1[r];
    __syncthreads();

    // ---- gate stage ----
    if (tid < 128) {
      float zr[4], zi[4];
#pragma unroll
      for (int q = 0; q < 4; ++q) {
        zr[q] = zp[gb][q * 8 + gu] + brg[q] +
                bf2f((unsigned short)(zv[q] & 0xFFFFu));
        zi[q] = zp[gb][32 + q * 8 + gu] + big[q] +
                bf2f((unsigned short)(zv[q] >> 16));
      }
      float ar = tanh_f(zr[0]), ai = tanh_f(zi[0]);
      float ir = sigm(zr[1]), ii = sigm(zi[1]);
      float fr = sigm(zr[2]), fi = sigm(zi[2]);
      float og_r = sigm(zr[3]), og_i = sigm(zi[3]);
      float ncr = ar * ir - ai * ii + fr * cr - fi * ci;
      float nci = ar * ii + ai * ir + fr * ci + fi * cr;
      cr = ncr;
      ci = nci;
      float tr = tanh_f(cr), ti = tanh_f(ci);
      float hr = og_r * tr - og_i * ti;
      float hi = og_r * ti + og_i * tr;

      float2 hv;
      hv.x = hr;
      hv.y = hi;
      *reinterpret_cast<float2*>(out + ((size_t)(gb * T_ + t) * U_ + u) * 2) = hv;

      unsigned short* hw = hb + (size_t)(par ^ 1) * (B_ * KP) + gb * KP;
      st_coh2(hw + u, (unsigned)f2bf(hr));
      st_coh2(hw + 512 + u, (unsigned)f2bf(hi));
    }

    // ---- release: drain own stores, then flag; poll peers; no fences ----
    wait_vm0();
    __syncthreads();
    if (tid == 0) st_coh4(&flags[g], t + 1);
    if (w == 0) {
      const int target = t + 1;
      while (true) {
        int v = ld_coh4(&flags[lane]);
        wait_vm0();
        if (__all(v >= target)) break;
        __builtin_amdgcn_s_sleep(1);
      }
    }
    __syncthreads();
  }
}

// ---------------------------------------------------------------------------
extern "C" void kernel_launch(void* const* d_in, const int* in_sizes, int n_in,
                              void* d_out, int out_size, void* d_ws, size_t ws_size,
                              hipStream_t stream) {
  const float* xr = (const float*)d_in[0];
  const float* xi = (const float*)d_in[1];
  const float* Wr = (const float*)d_in[2];
  const float* Wi = (const float*)d_in[3];
  const float* Ur = (const float*)d_in[4];
  const float* Ui = (const float*)d_in[5];
  const float* br = (const float*)d_in[6];
  const float* bi = (const float*)d_in[7];

  const size_t SZ_ZX = (size_t)M_ * G4 * 2 * 2;  // 262,144,000
  const size_t SZ_AB = (size_t)M_ * KP * 2;      //  65,536,000
  const size_t SZ_BT = (size_t)JP * KP * 2;      //   8,388,608
  const size_t SZ_HB = (size_t)2 * B_ * KP * 2;  //      65,536
  const size_t OFF_ZX = 0;
  const size_t OFF_AB = OFF_ZX + SZ_ZX;
  const size_t OFF_BW = OFF_AB + SZ_AB;
  const size_t OFF_BU = OFF_BW + SZ_BT;
  const size_t OFF_HB = OFF_BU + SZ_BT;
  const size_t OFF_FLAGS = OFF_HB + SZ_HB;
  const size_t NEEDED = OFF_FLAGS + 256;
  if (ws_size < NEEDED) return;  // insufficient scratch

  char* ws = (char*)d_ws;
  unsigned short* zx = (unsigned short*)(ws + OFF_ZX);
  unsigned short* Ab = (unsigned short*)(ws + OFF_AB);
  unsigned short* BtW = (unsigned short*)(ws + OFF_BW);
  unsigned short* BtU = (unsigned short*)(ws + OFF_BU);
  unsigned short* hb = (unsigned short*)(ws + OFF_HB);
  int* flags = (int*)(ws + OFF_FLAGS);

  // zero h0 state + flags (contiguous region), every launch (graph replay!)
  hipMemsetAsync(ws + OFF_HB, 0, SZ_HB + 256, stream);

  hipLaunchKernelGGL(k_convert_x, dim3(8000), dim3(256), 0, stream, xr, xi, Ab);
  hipLaunchKernelGGL(k_pack_B, dim3(16384), dim3(256), 0, stream, Wr, Wi, BtW);
  hipLaunchKernelGGL(k_pack_B, dim3(16384), dim3(256), 0, stream, Ur, Ui, BtU);
  hipLaunchKernelGGL(k_gemm_zx, dim3(250 * 32), dim3(256), 0, stream, Ab, BtW, zx);
  hipLaunchKernelGGL(k_scan, dim3(NBLK), dim3(256), 0, stream, zx, BtU, br, bi, hb,
                     (float*)d_out, flags);
}

// Round 4
// 10032.464 us; speedup vs baseline: 5.2683x; 1.0505x over previous
//
#include <hip/hip_runtime.h>
#include <cstdint>
#include <cstddef>

// Problem constants
#define B_   16
#define T_   2000
#define NIN  512
#define U_   512
#define G4   2048      // 4*U
#define KP   1024      // packed K (interleaved: k' = 2*u + plane)
#define JP   4096      // packed output cols (real plane | imag plane)
#define M_   32000     // B*T
#define NBLK 64        // scan blocks (one per CU, 8 units each)

typedef __attribute__((ext_vector_type(8))) short bf16x8;
typedef __attribute__((ext_vector_type(4))) float f32x4;

#define MFMA(a, b, c) __builtin_amdgcn_mfma_f32_16x16x32_bf16((a), (b), (c), 0, 0, 0)

__device__ __forceinline__ unsigned short f2bf(float f) {
  unsigned u = __builtin_bit_cast(unsigned, f);
  u = (u + 0x7FFFu + ((u >> 16) & 1u)) >> 16;
  return (unsigned short)u;
}
__device__ __forceinline__ float bf2f(unsigned short h) {
  unsigned u = ((unsigned)h) << 16;
  return __builtin_bit_cast(float, u);
}
__device__ __forceinline__ float sigm(float x) {
  return 1.0f / (1.0f + __expf(-x));
}
__device__ __forceinline__ float tanh_f(float x) {
  float cx = fminf(fmaxf(x, -15.0f), 15.0f);
  float e = __expf(2.0f * cx);
  return (e - 1.0f) / (e + 1.0f);
}

// --- coherence-point (L3) accessors: bypass L1/L2 via sc0 sc1 ---
__device__ __forceinline__ uint4 ld_coh16(const void* p) {
  uint4 r;
  asm volatile("global_load_dwordx4 %0, %1, off sc0 sc1"
               : "=v"(r) : "v"(p) : "memory");
  return r;
}
__device__ __forceinline__ int ld_coh4(const void* p) {
  int r;
  asm volatile("global_load_dword %0, %1, off sc0 sc1"
               : "=v"(r) : "v"(p) : "memory");
  return r;
}
__device__ __forceinline__ void st_coh4(void* p, int v) {
  asm volatile("global_store_dword %0, %1, off sc0 sc1"
               :: "v"(p), "v"(v) : "memory");
}
__device__ __forceinline__ void wait_vm0() {
  asm volatile("s_waitcnt vmcnt(0)" ::: "memory");
}

// ---------------------------------------------------------------------------
// Convert x fp32 [M,512]x2 -> packed A' bf16 [M,1024], k' = 2n+pl interleave:
//   A'[m][2n]   = xr[m][n]
//   A'[m][2n+1] = xi[m][n]
// ---------------------------------------------------------------------------
__global__ __launch_bounds__(256) void k_convert_x(const float* __restrict__ xr,
                                                   const float* __restrict__ xi,
                                                   unsigned short* __restrict__ Ab) {
  int i = blockIdx.x * 256 + threadIdx.x;
  int m = i >> 6;
  int k0 = (i & 63) << 3;  // n-base, 8 per thread
  if (m >= M_) return;
  const float* pr = xr + (size_t)m * NIN + k0;
  const float* pi = xi + (size_t)m * NIN + k0;
  float4 r0 = *reinterpret_cast<const float4*>(pr);
  float4 r1 = *reinterpret_cast<const float4*>(pr + 4);
  float4 i0 = *reinterpret_cast<const float4*>(pi);
  float4 i1 = *reinterpret_cast<const float4*>(pi + 4);
  uint4 v0, v1;
  v0.x = f2bf(r0.x) | ((unsigned)f2bf(i0.x) << 16);
  v0.y = f2bf(r0.y) | ((unsigned)f2bf(i0.y) << 16);
  v0.z = f2bf(r0.z) | ((unsigned)f2bf(i0.z) << 16);
  v0.w = f2bf(r0.w) | ((unsigned)f2bf(i0.w) << 16);
  v1.x = f2bf(r1.x) | ((unsigned)f2bf(i1.x) << 16);
  v1.y = f2bf(r1.y) | ((unsigned)f2bf(i1.y) << 16);
  v1.z = f2bf(r1.z) | ((unsigned)f2bf(i1.z) << 16);
  v1.w = f2bf(r1.w) | ((unsigned)f2bf(i1.w) << 16);
  unsigned short* dst = Ab + (size_t)m * KP + 2 * k0;
  *reinterpret_cast<uint4*>(dst) = v0;
  *reinterpret_cast<uint4*>(dst + 8) = v1;
}

// ---------------------------------------------------------------------------
// Pack complex weight [512,2048] into Bt bf16 [4096][1024], k' = 2u+pl:
//   jp = p*2048 + j:
//     p=0: pl=0 ->  Wr[u][j],  pl=1 -> -Wi[u][j]
//     p=1: pl=0 ->  Wi[u][j],  pl=1 ->  Wr[u][j]
// ---------------------------------------------------------------------------
__global__ __launch_bounds__(256) void k_pack_B(const float* __restrict__ Wr,
                                                const float* __restrict__ Wi,
                                                unsigned short* __restrict__ Bt) {
  int i = blockIdx.x * 256 + threadIdx.x;
  if (i >= JP * KP) return;
  int jp = i >> 10;
  int k = i & 1023;
  int p = jp >> 11;
  int j = jp & 2047;
  int u = k >> 1;
  int pl = k & 1;
  float v;
  if (p == 0) {
    v = pl ? -Wi[(size_t)u * G4 + j] : Wr[(size_t)u * G4 + j];
  } else {
    v = pl ? Wr[(size_t)u * G4 + j] : Wi[(size_t)u * G4 + j];
  }
  Bt[i] = f2bf(v);
}

// ---------------------------------------------------------------------------
// zx GEMM: A'[32000,1024] bf16 @ Bt[4096,1024]^T -> zx bf16 [T][B][2048][2]
// (K permutation is common to A' and Bt, so output is unchanged.)
// ---------------------------------------------------------------------------
__global__ __launch_bounds__(256) void k_gemm_zx(const unsigned short* __restrict__ A,
                                                 const unsigned short* __restrict__ Bt,
                                                 unsigned short* __restrict__ zx) {
  int bid = blockIdx.x;
  int nt = bid & 31;
  int mt = bid >> 5;
  int tid = threadIdx.x;
  int lane = tid & 63;
  int wid = tid >> 6;
  int wm = wid >> 1, wn = wid & 1;
  int l15 = lane & 15;
  int kb = (lane >> 4) << 3;
  int rowb = mt * 128 + wm * 64;
  int colb = nt * 128 + wn * 64;

  const unsigned short* ap[4];
  const unsigned short* bp[4];
#pragma unroll
  for (int x = 0; x < 4; ++x) {
    ap[x] = A + (size_t)(rowb + x * 16 + l15) * KP + kb;
    bp[x] = Bt + (size_t)(colb + x * 16 + l15) * KP + kb;
  }

  f32x4 acc[4][4];
#pragma unroll
  for (int mi = 0; mi < 4; ++mi)
#pragma unroll
    for (int ni = 0; ni < 4; ++ni) acc[mi][ni] = (f32x4){0.f, 0.f, 0.f, 0.f};

#pragma unroll 2
  for (int k = 0; k < KP; k += 32) {
    bf16x8 av[4], bv[4];
#pragma unroll
    for (int x = 0; x < 4; ++x) {
      av[x] = *reinterpret_cast<const bf16x8*>(ap[x] + k);
      bv[x] = *reinterpret_cast<const bf16x8*>(bp[x] + k);
    }
#pragma unroll
    for (int mi = 0; mi < 4; ++mi)
#pragma unroll
      for (int ni = 0; ni < 4; ++ni)
        acc[mi][ni] = MFMA(av[mi], bv[ni], acc[mi][ni]);
  }

  int rq = (lane >> 4) << 2;
#pragma unroll
  for (int mi = 0; mi < 4; ++mi) {
#pragma unroll
    for (int r = 0; r < 4; ++r) {
      int m = rowb + mi * 16 + rq + r;
      int bbv = m / T_;
      int tv = m - bbv * T_;
      size_t rowoff = (size_t)(tv * 16 + bbv) * (G4 * 2);
#pragma unroll
      for (int ni = 0; ni < 4; ++ni) {
        int jp2 = colb + ni * 16 + l15;
        int p = jp2 >> 11;
        int j = jp2 & 2047;
        zx[rowoff + (size_t)j * 2 + p] = f2bf(acc[mi][ni][r]);
      }
    }
  }
}

// ---------------------------------------------------------------------------
// Persistent scan v4. 64 blocks x 512 threads (8 waves, 2/SIMD), 1 block/CU.
// Block g owns units [8g,8g+8) -> 64 jp-rows. Wave w: row-group rg=w&3
// (16 rows), K-half kh=w>>2 (512 of 1024). uf[16] = 64 VGPR/thread, pinned.
// h layout: [par][b][k'=2u+pl] -> gate publish = ONE dword store per thread.
// out stores + zx[t+1] prefetch issued after flag publish (drain during poll).
// ---------------------------------------------------------------------------
__global__ __launch_bounds__(512, 1) void k_scan(const unsigned short* __restrict__ zx,
                                                 const unsigned short* __restrict__ Ub,
                                                 const float* __restrict__ brp,
                                                 const float* __restrict__ bip,
                                                 unsigned short* __restrict__ hb,
                                                 float* __restrict__ out,
                                                 int* __restrict__ flags) {
  const int g = blockIdx.x;
  const int tid = threadIdx.x;
  const int lane = tid & 63;
  const int w = tid >> 6;
  const int rg = w & 3;   // row-group
  const int kh = w >> 2;  // K-half
  const int l15 = lane & 15;

  __shared__ char lds_h[32768];   // 16 batches x 2048B (swizzled rows)
  __shared__ float zp[2][16][72]; // [khalf][batch][row], padded

  // --- U fragments: wave covers rows rg*16+l15, K-half kh. 16 frags = 64 VGPR.
  const int idx = rg * 16 + l15;  // jp-local row 0..63
  const int p_ = idx >> 5, gate_ = (idx >> 3) & 3, uu_ = idx & 7;
  const unsigned short* uptr = Ub +
      (size_t)(p_ * 2048 + gate_ * 512 + g * 8 + uu_) * KP + kh * 512 +
      ((lane >> 4) << 3);
  bf16x8 uf[16];
#pragma unroll
  for (int kk = 0; kk < 16; ++kk)
    uf[kk] = *reinterpret_cast<const bf16x8*>(uptr + kk * 32);
#pragma unroll
  for (int kk = 0; kk < 16; ++kk)
    asm volatile("" : "+v"(uf[kk]));  // pin: no remat into the T-loop

  // --- gate mapping (threads 0..127) ---
  const int gb = tid >> 3;   // batch
  const int gu = tid & 7;    // local unit
  const int u = g * 8 + gu;  // global unit
  float brg[4], big[4];
  if (tid < 128) {
#pragma unroll
    for (int q = 0; q < 4; ++q) {
      brg[q] = brp[q * 512 + u];
      big[q] = bip[q * 512 + u];
    }
  }
  float cr = 0.f, ci = 0.f;

  // --- stage addressing: 512 threads x 64B ---
  const int srow = tid >> 5;          // batch row 0..15
  const int sbase = (tid & 31) * 64;  // byte offset in 2048B row
  const int sswz = (srow & 7) << 4;

  // --- A-fragment read addressing ---
  const int arow = l15 * 2048;
  const int ainb = kh * 1024 + ((lane >> 4) << 4);  // in-row byte base
  const int aswz = (l15 & 7) << 4;

  // --- prologue: zx prefetch for t=0 ---
  unsigned zv[4];
  if (tid < 128) {
    const unsigned short* zt = zx + (size_t)(0 * 16 + gb) * (G4 * 2);
#pragma unroll
    for (int q = 0; q < 4; ++q)
      zv[q] = *reinterpret_cast<const unsigned*>(zt + (q * 512 + u) * 2);
  }

  for (int t = 0; t < T_; ++t) {
    const int par = t & 1;

    // ---- stage h[par] (L3 coherent) -> LDS swizzled ----
    const char* hsrc = (const char*)(hb + (size_t)par * (B_ * KP));
    uint4 sv[4];
#pragma unroll
    for (int j = 0; j < 4; ++j)
      sv[j] = ld_coh16(hsrc + srow * 2048 + sbase + j * 16);
    wait_vm0();  // also drains prev-iter out stores + zv prefetch
#pragma unroll
    for (int j = 0; j < 4; ++j)
      *reinterpret_cast<uint4*>(lds_h + srow * 2048 + ((sbase + j * 16) ^ sswz)) =
          sv[j];
    __syncthreads();

    // ---- MFMA: 16 k-iters (K-half), 2 chains ----
    f32x4 acc0 = {0.f, 0.f, 0.f, 0.f};
    f32x4 acc1 = {0.f, 0.f, 0.f, 0.f};
#pragma unroll
    for (int kk = 0; kk < 16; kk += 2) {
      bf16x8 a0 = *reinterpret_cast<const bf16x8*>(
          lds_h + arow + ((ainb + kk * 64) ^ aswz));
      bf16x8 a1 = *reinterpret_cast<const bf16x8*>(
          lds_h + arow + ((ainb + (kk + 1) * 64) ^ aswz));
      acc0 = MFMA(a0, uf[kk], acc0);
      acc1 = MFMA(a1, uf[kk + 1], acc1);
    }
    const int rq = (lane >> 4) << 2;
#pragma unroll
    for (int r = 0; r < 4; ++r)
      zp[kh][rq + r][idx] = acc0[r] + acc1[r];
    __syncthreads();

    float hr, hi;
    // ---- gate stage + h publish (one dword store) ----
    if (tid < 128) {
      float zr[4], zi[4];
#pragma unroll
      for (int q = 0; q < 4; ++q) {
        zr[q] = zp[0][gb][q * 8 + gu] + zp[1][gb][q * 8 + gu] + brg[q] +
                bf2f((unsigned short)(zv[q] & 0xFFFFu));
        zi[q] = zp[0][gb][32 + q * 8 + gu] + zp[1][gb][32 + q * 8 + gu] + big[q] +
                bf2f((unsigned short)(zv[q] >> 16));
      }
      float ar = tanh_f(zr[0]), ai = tanh_f(zi[0]);
      float ir = sigm(zr[1]), ii = sigm(zi[1]);
      float fr = sigm(zr[2]), fi = sigm(zi[2]);
      float og_r = sigm(zr[3]), og_i = sigm(zi[3]);
      float ncr = ar * ir - ai * ii + fr * cr - fi * ci;
      float nci = ar * ii + ai * ir + fr * ci + fi * cr;
      cr = ncr;
      ci = nci;
      float tr = tanh_f(cr), ti = tanh_f(ci);
      hr = og_r * tr - og_i * ti;
      hi = og_r * ti + og_i * tr;

      unsigned hv2 = (unsigned)f2bf(hr) | ((unsigned)f2bf(hi) << 16);
      unsigned* hw = (unsigned*)(hb + (size_t)(par ^ 1) * (B_ * KP) + gb * KP);
      st_coh4(hw + u, (int)hv2);
    }

    // ---- release: drain h stores, flag, then off-path work, then poll ----
    wait_vm0();
    __syncthreads();
    if (tid == 0) st_coh4(&flags[g], t + 1);
    if (tid < 128) {
      float2 hv;
      hv.x = hr;
      hv.y = hi;
      *reinterpret_cast<float2*>(out + ((size_t)(gb * T_ + t) * U_ + u) * 2) = hv;
      // prefetch zx for next step; drains during the poll
      int t1 = t + 1 < T_ ? t + 1 : t;
      const unsigned short* zt = zx + (size_t)(t1 * 16 + gb) * (G4 * 2);
#pragma unroll
      for (int q = 0; q < 4; ++q)
        zv[q] = *reinterpret_cast<const unsigned*>(zt + (q * 512 + u) * 2);
    }
    if (w == 0) {
      const int target = t + 1;
      while (true) {
        int v = ld_coh4(&flags[lane]);
        wait_vm0();
        if (__all(v >= target)) break;
        __builtin_amdgcn_s_sleep(1);
      }
    }
    __syncthreads();
  }
}

// ---------------------------------------------------------------------------
extern "C" void kernel_launch(void* const* d_in, const int* in_sizes, int n_in,
                              void* d_out, int out_size, void* d_ws, size_t ws_size,
                              hipStream_t stream) {
  const float* xr = (const float*)d_in[0];
  const float* xi = (const float*)d_in[1];
  const float* Wr = (const float*)d_in[2];
  const float* Wi = (const float*)d_in[3];
  const float* Ur = (const float*)d_in[4];
  const float* Ui = (const float*)d_in[5];
  const float* br = (const float*)d_in[6];
  const float* bi = (const float*)d_in[7];

  const size_t SZ_ZX = (size_t)M_ * G4 * 2 * 2;  // 262,144,000
  const size_t SZ_AB = (size_t)M_ * KP * 2;      //  65,536,000
  const size_t SZ_BT = (size_t)JP * KP * 2;      //   8,388,608
  const size_t SZ_HB = (size_t)2 * B_ * KP * 2;  //      65,536
  const size_t OFF_ZX = 0;
  const size_t OFF_AB = OFF_ZX + SZ_ZX;
  const size_t OFF_BW = OFF_AB + SZ_AB;
  const size_t OFF_BU = OFF_BW + SZ_BT;
  const size_t OFF_HB = OFF_BU + SZ_BT;
  const size_t OFF_FLAGS = OFF_HB + SZ_HB;
  const size_t NEEDED = OFF_FLAGS + 256;
  if (ws_size < NEEDED) return;  // insufficient scratch

  char* ws = (char*)d_ws;
  unsigned short* zx = (unsigned short*)(ws + OFF_ZX);
  unsigned short* Ab = (unsigned short*)(ws + OFF_AB);
  unsigned short* BtW = (unsigned short*)(ws + OFF_BW);
  unsigned short* BtU = (unsigned short*)(ws + OFF_BU);
  unsigned short* hb = (unsigned short*)(ws + OFF_HB);
  int* flags = (int*)(ws + OFF_FLAGS);

  // zero h0 state + flags (contiguous region), every launch (graph replay!)
  hipMemsetAsync(ws + OFF_HB, 0, SZ_HB + 256, stream);

  hipLaunchKernelGGL(k_convert_x, dim3(8000), dim3(256), 0, stream, xr, xi, Ab);
  hipLaunchKernelGGL(k_pack_B, dim3(16384), dim3(256), 0, stream, Wr, Wi, BtW);
  hipLaunchKernelGGL(k_pack_B, dim3(16384), dim3(256), 0, stream, Ur, Ui, BtU);
  hipLaunchKernelGGL(k_gemm_zx, dim3(250 * 32), dim3(256), 0, stream, Ab, BtW, zx);
  hipLaunchKernelGGL(k_scan, dim3(NBLK), dim3(512), 0, stream, zx, BtU, br, bi, hb,
                     (float*)d_out, flags);
}

// Round 5
// 7241.287 us; speedup vs baseline: 7.2990x; 1.3855x over previous
//
#include <hip/hip_runtime.h>
#include <cstdint>
#include <cstddef>

// Problem constants
#define B_   16
#define T_   2000
#define NIN  512
#define U_   512
#define G4   2048      // 4*U
#define KP   1024      // packed K (interleaved: k' = 2*u + plane)
#define JP   4096      // packed output cols (real plane | imag plane)
#define M_   32000     // B*T
#define NGRP 8         // scan groups (one per XCD expected)
#define MPG  32        // members (blocks/CUs) per group
#define SCAN_BLOCKS (NGRP * MPG)

typedef __attribute__((ext_vector_type(8))) short bf16x8;
typedef __attribute__((ext_vector_type(4))) float f32x4;

#define MFMA(a, b, c) __builtin_amdgcn_mfma_f32_16x16x32_bf16((a), (b), (c), 0, 0, 0)

__device__ __forceinline__ unsigned short f2bf(float f) {
  unsigned u = __builtin_bit_cast(unsigned, f);
  u = (u + 0x7FFFu + ((u >> 16) & 1u)) >> 16;
  return (unsigned short)u;
}
__device__ __forceinline__ float bf2f(unsigned short h) {
  unsigned u = ((unsigned)h) << 16;
  return __builtin_bit_cast(float, u);
}
__device__ __forceinline__ float sigm(float x) {
  return 1.0f / (1.0f + __expf(-x));
}
__device__ __forceinline__ float tanh_f(float x) {
  float cx = fminf(fmaxf(x, -15.0f), 15.0f);
  float e = __expf(2.0f * cx);
  return (e - 1.0f) / (e + 1.0f);
}

// --- L2-point (XCD-local) accessors: sc0 = L1-bypass, serviced at L2 ---
__device__ __forceinline__ uint4 ld16_l2(const void* p) {
  uint4 r;
  asm volatile("global_load_dwordx4 %0, %1, off sc0" : "=v"(r) : "v"(p) : "memory");
  return r;
}
__device__ __forceinline__ int ld4_l2(const void* p) {
  int r;
  asm volatile("global_load_dword %0, %1, off sc0" : "=v"(r) : "v"(p) : "memory");
  return r;
}
__device__ __forceinline__ void st4_l2(void* p, int v) {
  asm volatile("global_store_dword %0, %1, off sc0" :: "v"(p), "v"(v) : "memory");
}
// --- L3-point (cross-XCD safe) accessors: sc0 sc1 ---
__device__ __forceinline__ uint4 ld16_l3(const void* p) {
  uint4 r;
  asm volatile("global_load_dwordx4 %0, %1, off sc0 sc1" : "=v"(r) : "v"(p) : "memory");
  return r;
}
__device__ __forceinline__ int ld4_l3(const void* p) {
  int r;
  asm volatile("global_load_dword %0, %1, off sc0 sc1" : "=v"(r) : "v"(p) : "memory");
  return r;
}
__device__ __forceinline__ void st4_l3(void* p, int v) {
  asm volatile("global_store_dword %0, %1, off sc0 sc1" :: "v"(p), "v"(v) : "memory");
}
__device__ __forceinline__ void wait_vm0() {
  asm volatile("s_waitcnt vmcnt(0)" ::: "memory");
}

// ---------------------------------------------------------------------------
// Convert x fp32 [M,512]x2 -> packed A' bf16 [M,1024], k' = 2n+pl interleave.
// ---------------------------------------------------------------------------
__global__ __launch_bounds__(256) void k_convert_x(const float* __restrict__ xr,
                                                   const float* __restrict__ xi,
                                                   unsigned short* __restrict__ Ab) {
  int i = blockIdx.x * 256 + threadIdx.x;
  int m = i >> 6;
  int k0 = (i & 63) << 3;  // n-base, 8 per thread
  if (m >= M_) return;
  const float* pr = xr + (size_t)m * NIN + k0;
  const float* pi = xi + (size_t)m * NIN + k0;
  float4 r0 = *reinterpret_cast<const float4*>(pr);
  float4 r1 = *reinterpret_cast<const float4*>(pr + 4);
  float4 i0 = *reinterpret_cast<const float4*>(pi);
  float4 i1 = *reinterpret_cast<const float4*>(pi + 4);
  uint4 v0, v1;
  v0.x = f2bf(r0.x) | ((unsigned)f2bf(i0.x) << 16);
  v0.y = f2bf(r0.y) | ((unsigned)f2bf(i0.y) << 16);
  v0.z = f2bf(r0.z) | ((unsigned)f2bf(i0.z) << 16);
  v0.w = f2bf(r0.w) | ((unsigned)f2bf(i0.w) << 16);
  v1.x = f2bf(r1.x) | ((unsigned)f2bf(i1.x) << 16);
  v1.y = f2bf(r1.y) | ((unsigned)f2bf(i1.y) << 16);
  v1.z = f2bf(r1.z) | ((unsigned)f2bf(i1.z) << 16);
  v1.w = f2bf(r1.w) | ((unsigned)f2bf(i1.w) << 16);
  unsigned short* dst = Ab + (size_t)m * KP + 2 * k0;
  *reinterpret_cast<uint4*>(dst) = v0;
  *reinterpret_cast<uint4*>(dst + 8) = v1;
}

// ---------------------------------------------------------------------------
// Pack complex weight [512,2048] into Bt bf16 [4096][1024], k' = 2u+pl.
// ---------------------------------------------------------------------------
__global__ __launch_bounds__(256) void k_pack_B(const float* __restrict__ Wr,
                                                const float* __restrict__ Wi,
                                                unsigned short* __restrict__ Bt) {
  int i = blockIdx.x * 256 + threadIdx.x;
  if (i >= JP * KP) return;
  int jp = i >> 10;
  int k = i & 1023;
  int p = jp >> 11;
  int j = jp & 2047;
  int u = k >> 1;
  int pl = k & 1;
  float v;
  if (p == 0) {
    v = pl ? -Wi[(size_t)u * G4 + j] : Wr[(size_t)u * G4 + j];
  } else {
    v = pl ? Wr[(size_t)u * G4 + j] : Wi[(size_t)u * G4 + j];
  }
  Bt[i] = f2bf(v);
}

// ---------------------------------------------------------------------------
// zx GEMM: A'[32000,1024] bf16 @ Bt[4096,1024]^T -> zx bf16 [T][B][2048][2]
// ---------------------------------------------------------------------------
__global__ __launch_bounds__(256) void k_gemm_zx(const unsigned short* __restrict__ A,
                                                 const unsigned short* __restrict__ Bt,
                                                 unsigned short* __restrict__ zx) {
  int bid = blockIdx.x;
  int nt = bid & 31;
  int mt = bid >> 5;
  int tid = threadIdx.x;
  int lane = tid & 63;
  int wid = tid >> 6;
  int wm = wid >> 1, wn = wid & 1;
  int l15 = lane & 15;
  int kb = (lane >> 4) << 3;
  int rowb = mt * 128 + wm * 64;
  int colb = nt * 128 + wn * 64;

  const unsigned short* ap[4];
  const unsigned short* bp[4];
#pragma unroll
  for (int x = 0; x < 4; ++x) {
    ap[x] = A + (size_t)(rowb + x * 16 + l15) * KP + kb;
    bp[x] = Bt + (size_t)(colb + x * 16 + l15) * KP + kb;
  }

  f32x4 acc[4][4];
#pragma unroll
  for (int mi = 0; mi < 4; ++mi)
#pragma unroll
    for (int ni = 0; ni < 4; ++ni) acc[mi][ni] = (f32x4){0.f, 0.f, 0.f, 0.f};

#pragma unroll 2
  for (int k = 0; k < KP; k += 32) {
    bf16x8 av[4], bv[4];
#pragma unroll
    for (int x = 0; x < 4; ++x) {
      av[x] = *reinterpret_cast<const bf16x8*>(ap[x] + k);
      bv[x] = *reinterpret_cast<const bf16x8*>(bp[x] + k);
    }
#pragma unroll
    for (int mi = 0; mi < 4; ++mi)
#pragma unroll
      for (int ni = 0; ni < 4; ++ni)
        acc[mi][ni] = MFMA(av[mi], bv[ni], acc[mi][ni]);
  }

  int rq = (lane >> 4) << 2;
#pragma unroll
  for (int mi = 0; mi < 4; ++mi) {
#pragma unroll
    for (int r = 0; r < 4; ++r) {
      int m = rowb + mi * 16 + rq + r;
      int bbv = m / T_;
      int tv = m - bbv * T_;
      size_t rowoff = (size_t)(tv * 16 + bbv) * (G4 * 2);
#pragma unroll
      for (int ni = 0; ni < 4; ++ni) {
        int jp2 = colb + ni * 16 + l15;
        int p = jp2 >> 11;
        int j = jp2 & 2047;
        zx[rowoff + (size_t)j * 2 + p] = f2bf(acc[mi][ni][r]);
      }
    }
  }
}

// ---------------------------------------------------------------------------
// Persistent scan v5 — XCD-local groups.
// 256 blocks x 512 threads (1/CU, all co-resident). Group g = bid&7 (32
// members, same XCD under measured round-robin dispatch) owns global batches
// {2g, 2g+1} and runs a fully independent recurrence. Member m = bid>>3 owns
// units [16m,16m+16): 128 jp-rows of U = 32 pinned bf16x8/thread (full U in
// the group's registers). Per step: stage 4KB h from group buffer (L2 via
// sc0 when local), 32 MFMAs/wave (A rows 0-1 = the 2 batches), gate on 32
// threads, publish 128B h, member-flag barrier polled by wave 7.
// One-time 4-round sc0 token handshake decides lok; fallback = sc0 sc1 (L3),
// correct for any placement.
// ---------------------------------------------------------------------------
__global__ __launch_bounds__(512, 2) void k_scan(
    const unsigned short* __restrict__ zx,
    const unsigned short* __restrict__ Ub,
    const float* __restrict__ brp,
    const float* __restrict__ bip,
    unsigned short* __restrict__ hb,  // [NGRP][2 par][2 b][1024] bf16
    float* __restrict__ out,
    int* __restrict__ flags,          // [NGRP][MPG]
    int* __restrict__ tok,            // [NGRP][MPG]
    int* __restrict__ ctl) {          // [0]=arrive, [8+g]=group-bad
  const int bid = blockIdx.x;
  const int tid = threadIdx.x;
  const int lane = tid & 63;
  const int w = tid >> 6;
  const int l15 = lane & 15;
  const int g = bid & 7;
  const int m = bid >> 3;

  __shared__ char lds_h[4096];     // h staged: [2 b][1024] bf16
  __shared__ float zp[2][132];     // z exchange: [b][tile*16+col]
  __shared__ int s_ok;

  int* gtok = tok + g * MPG;
  int* gflags = flags + g * MPG;
  char* hgrp = (char*)hb + g * 8192;

  // ==== one-time locality handshake (exactly the in-loop op flavors) ====
  int myok = 1;
  for (int r = 1; r <= 4 && myok; ++r) {
    if (tid == 0) st4_l2(&gtok[m], r);
    if (w == 0) {
      int pass = 0;
      for (int it = 0; it < 1500; ++it) {
        int v = ld4_l2(&gtok[lane & 31]);
        wait_vm0();
        if (__all(v >= r)) { pass = 1; break; }
        __builtin_amdgcn_s_sleep(2);
      }
      myok = pass;
    }
  }
  if (tid == 0 && !myok) st4_l3(&ctl[8 + g], 1);
  wait_vm0();
  __syncthreads();
  if (tid == 0) {
    __hip_atomic_fetch_add(&ctl[0], 1, __ATOMIC_RELAXED, __HIP_MEMORY_SCOPE_AGENT);
    while (true) {
      int v = ld4_l3(&ctl[0]);
      wait_vm0();
      if (v == SCAN_BLOCKS) break;
      __builtin_amdgcn_s_sleep(2);
    }
    int bad = ld4_l3(&ctl[8 + g]);
    wait_vm0();
    s_ok = bad ? 0 : 1;
  }
  __syncthreads();
  const bool lok = (s_ok != 0);

  // ==== U fragments: wave w <-> tile (p=w>>2, q=w&3), 16 units, K=1024 ====
  const int p_ = w >> 2, q_ = w & 3;
  const unsigned short* uptr =
      Ub + (size_t)(p_ * 2048 + q_ * 512 + m * 16 + l15) * KP + ((lane >> 4) << 3);
  bf16x8 uf[32];
#pragma unroll
  for (int kk = 0; kk < 32; ++kk)
    uf[kk] = *reinterpret_cast<const bf16x8*>(uptr + kk * 32);
#pragma unroll
  for (int kk = 0; kk < 32; ++kk)
    asm volatile("" : "+v"(uf[kk]));  // pin against rematerialization

  // ==== gate mapping (threads 0..31): (local batch, local unit) ====
  const int gb = tid >> 4;        // 0..1
  const int gu = tid & 15;        // 0..15
  const int u = m * 16 + gu;      // global unit
  const int bglob = g * 2 + gb;   // global batch
  float brg[4], big[4];
  if (tid < 32) {
#pragma unroll
    for (int q = 0; q < 4; ++q) {
      brg[q] = brp[q * 512 + u];
      big[q] = bip[q * 512 + u];
    }
  }
  float cr = 0.f, ci = 0.f;

  // stage role: waves 1-4 (256 threads x 16B = 4KB)
  const int stq = (tid >= 64 && tid < 320) ? (tid - 64) : -1;

  // A-fragment read addressing: row = batch (l15&1), k-chunk by lane>>4
  const int arow = (l15 & 1) * 2048;
  const int achunk = (lane >> 4) * 16;

  // zx prologue (2-deep pipeline: zvA = even t, zvB = odd t)
  unsigned zvA[4], zvB[4];
  if (tid < 32) {
    const unsigned* zt0 = (const unsigned*)zx + (size_t)(0 * 16 + bglob) * 2048;
    const unsigned* zt1 = (const unsigned*)zx + (size_t)(1 * 16 + bglob) * 2048;
#pragma unroll
    for (int q = 0; q < 4; ++q) {
      zvA[q] = zt0[q * 512 + u];
      zvB[q] = zt1[q * 512 + u];
    }
  }

#define STEP(TCUR, PARC, ZV)                                                   \
  {                                                                            \
    if (stq >= 0) {                                                            \
      const char* hsrc = hgrp + (PARC) * 4096 + stq * 16;                      \
      uint4 sv = lok ? ld16_l2(hsrc) : ld16_l3(hsrc);                          \
      wait_vm0();                                                              \
      *reinterpret_cast<uint4*>(lds_h + stq * 16) = sv;                        \
    }                                                                          \
    __syncthreads();                                                           \
    f32x4 acc0 = {0.f, 0.f, 0.f, 0.f};                                         \
    f32x4 acc1 = {0.f, 0.f, 0.f, 0.f};                                         \
    _Pragma("unroll")                                                          \
    for (int kk = 0; kk < 32; kk += 2) {                                       \
      bf16x8 a0 = *reinterpret_cast<const bf16x8*>(                            \
          lds_h + arow + kk * 64 + achunk);                                    \
      bf16x8 a1 = *reinterpret_cast<const bf16x8*>(                            \
          lds_h + arow + (kk + 1) * 64 + achunk);                              \
      acc0 = MFMA(a0, uf[kk], acc0);                                           \
      acc1 = MFMA(a1, uf[kk + 1], acc1);                                       \
    }                                                                          \
    if (lane < 16) {                                                           \
      zp[0][w * 16 + lane] = acc0[0] + acc1[0];                                \
      zp[1][w * 16 + lane] = acc0[1] + acc1[1];                                \
    }                                                                          \
    __syncthreads();                                                           \
    if (tid < 32) {                                                            \
      float zr[4], zi[4];                                                      \
      _Pragma("unroll")                                                        \
      for (int q = 0; q < 4; ++q) {                                            \
        zr[q] = zp[gb][q * 16 + gu] + brg[q] +                                 \
                bf2f((unsigned short)((ZV)[q] & 0xFFFFu));                     \
        zi[q] = zp[gb][64 + q * 16 + gu] + big[q] +                            \
                bf2f((unsigned short)((ZV)[q] >> 16));                         \
      }                                                                        \
      float ar = tanh_f(zr[0]), ai = tanh_f(zi[0]);                            \
      float ir = sigm(zr[1]), ii = sigm(zi[1]);                                \
      float fr = sigm(zr[2]), fi = sigm(zi[2]);                                \
      float og_r = sigm(zr[3]), og_i = sigm(zi[3]);                            \
      float ncr = ar * ir - ai * ii + fr * cr - fi * ci;                       \
      float nci = ar * ii + ai * ir + fr * ci + fi * cr;                       \
      cr = ncr; ci = nci;                                                      \
      float tr = tanh_f(cr), ti = tanh_f(ci);                                  \
      float hr = og_r * tr - og_i * ti;                                        \
      float hi = og_r * ti + og_i * tr;                                        \
      unsigned hv2 = (unsigned)f2bf(hr) | ((unsigned)f2bf(hi) << 16);          \
      char* hp = hgrp + ((PARC) ^ 1) * 4096 + gb * 2048 + u * 4;               \
      if (lok) st4_l2(hp, (int)hv2); else st4_l3(hp, (int)hv2);                \
      wait_vm0();                                                              \
      float2 hv;                                                               \
      hv.x = hr;                                                               \
      hv.y = hi;                                                               \
      *reinterpret_cast<float2*>(                                              \
          out + ((size_t)(bglob * T_ + (TCUR)) * U_ + u) * 2) = hv;            \
    }                                                                          \
    __syncthreads();                                                           \
    if (tid == 448) {                                                          \
      if (lok) st4_l2(&gflags[m], (TCUR) + 1);                                 \
      else st4_l3(&gflags[m], (TCUR) + 1);                                     \
    }                                                                          \
    if (tid < 32) {                                                            \
      int tp = (TCUR) + 2 < T_ ? (TCUR) + 2 : (TCUR);                          \
      const unsigned* zt =                                                     \
          (const unsigned*)zx + (size_t)(tp * 16 + bglob) * 2048;              \
      _Pragma("unroll")                                                        \
      for (int q = 0; q < 4; ++q) (ZV)[q] = zt[q * 512 + u];                   \
    }                                                                          \
    if (w == 7) {                                                              \
      const int target = (TCUR) + 1;                                           \
      while (true) {                                                           \
        int v = lok ? ld4_l2(&gflags[lane & 31]) : ld4_l3(&gflags[lane & 31]); \
        wait_vm0();                                                            \
        if (__all(v >= target)) break;                                         \
      }                                                                        \
    }                                                                          \
    __syncthreads();                                                           \
  }

  for (int t = 0; t < T_; t += 2) {
    STEP(t, 0, zvA);
    STEP(t + 1, 1, zvB);
  }
#undef STEP
}

// ---------------------------------------------------------------------------
extern "C" void kernel_launch(void* const* d_in, const int* in_sizes, int n_in,
                              void* d_out, int out_size, void* d_ws, size_t ws_size,
                              hipStream_t stream) {
  const float* xr = (const float*)d_in[0];
  const float* xi = (const float*)d_in[1];
  const float* Wr = (const float*)d_in[2];
  const float* Wi = (const float*)d_in[3];
  const float* Ur = (const float*)d_in[4];
  const float* Ui = (const float*)d_in[5];
  const float* br = (const float*)d_in[6];
  const float* bi = (const float*)d_in[7];

  const size_t SZ_ZX = (size_t)M_ * G4 * 2 * 2;      // 262,144,000
  const size_t SZ_AB = (size_t)M_ * KP * 2;          //  65,536,000
  const size_t SZ_BT = (size_t)JP * KP * 2;          //   8,388,608
  const size_t SZ_HB = (size_t)NGRP * 8192;          //      65,536
  const size_t SZ_FLAGS = (size_t)NGRP * MPG * 4;    //       1,024
  const size_t SZ_TOK = (size_t)NGRP * MPG * 4;      //       1,024
  const size_t SZ_CTL = 64;
  const size_t OFF_ZX = 0;
  const size_t OFF_AB = OFF_ZX + SZ_ZX;
  const size_t OFF_BW = OFF_AB + SZ_AB;
  const size_t OFF_BU = OFF_BW + SZ_BT;
  const size_t OFF_HB = OFF_BU + SZ_BT;
  const size_t OFF_FLAGS = OFF_HB + SZ_HB;
  const size_t OFF_TOK = OFF_FLAGS + SZ_FLAGS;
  const size_t OFF_CTL = OFF_TOK + SZ_TOK;
  const size_t NEEDED = OFF_CTL + SZ_CTL;
  if (ws_size < NEEDED) return;  // insufficient scratch

  char* ws = (char*)d_ws;
  unsigned short* zx = (unsigned short*)(ws + OFF_ZX);
  unsigned short* Ab = (unsigned short*)(ws + OFF_AB);
  unsigned short* BtW = (unsigned short*)(ws + OFF_BW);
  unsigned short* BtU = (unsigned short*)(ws + OFF_BU);
  unsigned short* hb = (unsigned short*)(ws + OFF_HB);
  int* flags = (int*)(ws + OFF_FLAGS);
  int* tokp = (int*)(ws + OFF_TOK);
  int* ctl = (int*)(ws + OFF_CTL);

  // zero h0 + flags + tokens + counters, every launch (graph replay!)
  hipMemsetAsync(ws + OFF_HB, 0, SZ_HB + SZ_FLAGS + SZ_TOK + SZ_CTL, stream);

  hipLaunchKernelGGL(k_convert_x, dim3(8000), dim3(256), 0, stream, xr, xi, Ab);
  hipLaunchKernelGGL(k_pack_B, dim3(16384), dim3(256), 0, stream, Wr, Wi, BtW);
  hipLaunchKernelGGL(k_pack_B, dim3(16384), dim3(256), 0, stream, Ur, Ui, BtU);
  hipLaunchKernelGGL(k_gemm_zx, dim3(250 * 32), dim3(256), 0, stream, Ab, BtW, zx);
  hipLaunchKernelGGL(k_scan, dim3(SCAN_BLOCKS), dim3(512), 0, stream, zx, BtU,
                     br, bi, hb, (float*)d_out, flags, tokp, ctl);
}

// Round 8
// 5415.830 us; speedup vs baseline: 9.7592x; 1.3371x over previous
//
#include <hip/hip_runtime.h>
#include <cstdint>
#include <cstddef>

// Problem constants
#define B_   16
#define T_   2000
#define NIN  512
#define U_   512
#define G4   2048      // 4*U
#define KP   1024      // packed K (interleaved: k' = 2*u + plane)
#define JP   4096      // packed output cols (real plane | imag plane)
#define M_   32000     // B*T
#define NGRP 8         // scan groups
#define MPG  32        // members per group
#define SCAN_BLOCKS (NGRP * MPG)
#define LDSROW 2112    // lds_h row stride (row 1 shifted to banks 16..31)

typedef __attribute__((ext_vector_type(8))) short bf16x8;
typedef __attribute__((ext_vector_type(4))) float f32x4;
typedef __attribute__((ext_vector_type(2))) int i32x2;

#define MFMA(a, b, c) __builtin_amdgcn_mfma_f32_16x16x32_bf16((a), (b), (c), 0, 0, 0)

__device__ __forceinline__ unsigned short f2bf(float f) {
  unsigned u = __builtin_bit_cast(unsigned, f);
  u = (u + 0x7FFFu + ((u >> 16) & 1u)) >> 16;
  return (unsigned short)u;
}
__device__ __forceinline__ float bf2f(unsigned short h) {
  unsigned u = ((unsigned)h) << 16;
  return __builtin_bit_cast(float, u);
}
__device__ __forceinline__ float sigm(float x) {
  return 1.0f / (1.0f + __expf(-x));
}
__device__ __forceinline__ float tanh_f(float x) {
  float cx = fminf(fmaxf(x, -15.0f), 15.0f);
  float e = __expf(2.0f * cx);
  return (e - 1.0f) / (e + 1.0f);
}

// --- L3-point (coherence point, cross-XCD safe) accessors: sc0 sc1 ---
// RULE #18 HARDENED: loads and their s_waitcnt live in ONE asm block with
// early-clobber outputs, so the dest VGPRs are architecturally valid at asm
// exit; sched_barrier(0) stops hipcc re-scheduling register-only consumers
// into the (now nonexistent) load-shadow.
__device__ __forceinline__ void ld32_l3_sync(const void* p, uint4& a, uint4& b) {
  asm volatile("global_load_dwordx4 %0, %2, off sc0 sc1\n\t"
               "global_load_dwordx4 %1, %3, off sc0 sc1\n\t"
               "s_waitcnt vmcnt(0)"
               : "=&v"(a), "=&v"(b)
               : "v"(p), "v"((const void*)((const char*)p + 16))
               : "memory");
  __builtin_amdgcn_sched_barrier(0);
}
__device__ __forceinline__ void st8_l3(void* p, i32x2 v) {
  asm volatile("global_store_dwordx2 %0, %1, off sc0 sc1" :: "v"(p), "v"(v) : "memory");
}

// ---------------------------------------------------------------------------
// Convert x fp32 [M,512]x2 -> packed A' bf16 [M,1024], k' = 2n+pl interleave.
// ---------------------------------------------------------------------------
__global__ __launch_bounds__(256) void k_convert_x(const float* __restrict__ xr,
                                                   const float* __restrict__ xi,
                                                   unsigned short* __restrict__ Ab) {
  int i = blockIdx.x * 256 + threadIdx.x;
  int m = i >> 6;
  int k0 = (i & 63) << 3;  // n-base, 8 per thread
  if (m >= M_) return;
  const float* pr = xr + (size_t)m * NIN + k0;
  const float* pi = xi + (size_t)m * NIN + k0;
  float4 r0 = *reinterpret_cast<const float4*>(pr);
  float4 r1 = *reinterpret_cast<const float4*>(pr + 4);
  float4 i0 = *reinterpret_cast<const float4*>(pi);
  float4 i1 = *reinterpret_cast<const float4*>(pi + 4);
  uint4 v0, v1;
  v0.x = f2bf(r0.x) | ((unsigned)f2bf(i0.x) << 16);
  v0.y = f2bf(r0.y) | ((unsigned)f2bf(i0.y) << 16);
  v0.z = f2bf(r0.z) | ((unsigned)f2bf(i0.z) << 16);
  v0.w = f2bf(r0.w) | ((unsigned)f2bf(i0.w) << 16);
  v1.x = f2bf(r1.x) | ((unsigned)f2bf(i1.x) << 16);
  v1.y = f2bf(r1.y) | ((unsigned)f2bf(i1.y) << 16);
  v1.z = f2bf(r1.z) | ((unsigned)f2bf(i1.z) << 16);
  v1.w = f2bf(r1.w) | ((unsigned)f2bf(i1.w) << 16);
  unsigned short* dst = Ab + (size_t)m * KP + 2 * k0;
  *reinterpret_cast<uint4*>(dst) = v0;
  *reinterpret_cast<uint4*>(dst + 8) = v1;
}

// ---------------------------------------------------------------------------
// Pack complex weight [512,2048] into Bt bf16 [4096][1024], k' = 2u+pl.
// ---------------------------------------------------------------------------
__global__ __launch_bounds__(256) void k_pack_B(const float* __restrict__ Wr,
                                                const float* __restrict__ Wi,
                                                unsigned short* __restrict__ Bt) {
  int i = blockIdx.x * 256 + threadIdx.x;
  if (i >= JP * KP) return;
  int jp = i >> 10;
  int k = i & 1023;
  int p = jp >> 11;
  int j = jp & 2047;
  int u = k >> 1;
  int pl = k & 1;
  float v;
  if (p == 0) {
    v = pl ? -Wi[(size_t)u * G4 + j] : Wr[(size_t)u * G4 + j];
  } else {
    v = pl ? Wr[(size_t)u * G4 + j] : Wi[(size_t)u * G4 + j];
  }
  Bt[i] = f2bf(v);
}

// ---------------------------------------------------------------------------
// zx GEMM: A'[32000,1024] bf16 @ Bt[4096,1024]^T -> zx bf16 [T][B][2048][2]
// ---------------------------------------------------------------------------
__global__ __launch_bounds__(256) void k_gemm_zx(const unsigned short* __restrict__ A,
                                                 const unsigned short* __restrict__ Bt,
                                                 unsigned short* __restrict__ zx) {
  int bid = blockIdx.x;
  int nt = bid & 31;
  int mt = bid >> 5;
  int tid = threadIdx.x;
  int lane = tid & 63;
  int wid = tid >> 6;
  int wm = wid >> 1, wn = wid & 1;
  int l15 = lane & 15;
  int kb = (lane >> 4) << 3;
  int rowb = mt * 128 + wm * 64;
  int colb = nt * 128 + wn * 64;

  const unsigned short* ap[4];
  const unsigned short* bp[4];
#pragma unroll
  for (int x = 0; x < 4; ++x) {
    ap[x] = A + (size_t)(rowb + x * 16 + l15) * KP + kb;
    bp[x] = Bt + (size_t)(colb + x * 16 + l15) * KP + kb;
  }

  f32x4 acc[4][4];
#pragma unroll
  for (int mi = 0; mi < 4; ++mi)
#pragma unroll
    for (int ni = 0; ni < 4; ++ni) acc[mi][ni] = (f32x4){0.f, 0.f, 0.f, 0.f};

#pragma unroll 2
  for (int k = 0; k < KP; k += 32) {
    bf16x8 av[4], bv[4];
#pragma unroll
    for (int x = 0; x < 4; ++x) {
      av[x] = *reinterpret_cast<const bf16x8*>(ap[x] + k);
      bv[x] = *reinterpret_cast<const bf16x8*>(bp[x] + k);
    }
#pragma unroll
    for (int mi = 0; mi < 4; ++mi)
#pragma unroll
      for (int ni = 0; ni < 4; ++ni)
        acc[mi][ni] = MFMA(av[mi], bv[ni], acc[mi][ni]);
  }

  int rq = (lane >> 4) << 2;
#pragma unroll
  for (int mi = 0; mi < 4; ++mi) {
#pragma unroll
    for (int r = 0; r < 4; ++r) {
      int m = rowb + mi * 16 + rq + r;
      int bbv = m / T_;
      int tv = m - bbv * T_;
      size_t rowoff = (size_t)(tv * 16 + bbv) * (G4 * 2);
#pragma unroll
      for (int ni = 0; ni < 4; ++ni) {
        int jp2 = colb + ni * 16 + l15;
        int p = jp2 >> 11;
        int j = jp2 & 2047;
        zx[rowoff + (size_t)j * 2 + p] = f2bf(acc[mi][ni][r]);
      }
    }
  }
}

// ---------------------------------------------------------------------------
// Persistent scan v8 = v7 (tag-fused barrier, L3 path, no prologue) with the
// rule-#18-hardened poll: load+waitcnt fused in one asm block.
// 256 blocks x 512 threads. Group g = bid&7 owns batches {2g,2g+1}; member
// m = bid>>3 owns units [16m,16m+16) -> 128 jp-rows of U pinned in registers.
// h exchange: [g][par][gb*512+u] 8B records {h bf16x2, tag=t+1}; 256 stager
// threads poll 32B chunks (4 records, one member each) until tags >= t --
// the successful poll IS the stage load. Monotone >= polls: replay-safe.
// ---------------------------------------------------------------------------
__global__ __launch_bounds__(512, 2) void k_scan(
    const unsigned short* __restrict__ zx,
    const unsigned short* __restrict__ Ub,
    const float* __restrict__ brp,
    const float* __restrict__ bip,
    char* __restrict__ hb2,   // [NGRP][2 par][1024 records][8B]
    float* __restrict__ out) {
  const int bid = blockIdx.x;
  const int tid = threadIdx.x;
  const int lane = tid & 63;
  const int w = tid >> 6;
  const int l15 = lane & 15;
  const int g = bid & 7;
  const int m = bid >> 3;

  __shared__ char lds_h[2 * LDSROW];  // [2 batch rows][2048B h], stride 2112
  __shared__ float zp[2][132];        // z exchange [batch][row]

  // ---- U fragments: wave w -> (plane p_=w>>2, gate q_=w&3), 16 units ----
  const int p_ = w >> 2, q_ = w & 3;
  const unsigned short* uptr =
      Ub + (size_t)(p_ * 2048 + q_ * 512 + m * 16 + l15) * KP + ((lane >> 4) << 3);
  bf16x8 uf[32];
#pragma unroll
  for (int kk = 0; kk < 32; ++kk)
    uf[kk] = *reinterpret_cast<const bf16x8*>(uptr + kk * 32);
#pragma unroll
  for (int kk = 0; kk < 32; ++kk)
    asm volatile("" : "+v"(uf[kk]));  // pin against rematerialization

  // ---- gate mapping (threads 0..31) ----
  const int gb = tid >> 4;        // local batch 0..1
  const int gu = tid & 15;        // local unit 0..15
  const int u = m * 16 + gu;      // global unit
  const int bglob = g * 2 + gb;   // global batch
  float brg[4], big[4];
  if (tid < 32) {
#pragma unroll
    for (int q = 0; q < 4; ++q) {
      brg[q] = brp[q * 512 + u];
      big[q] = bip[q * 512 + u];
    }
  }
  float cr = 0.f, ci = 0.f;

  char* hgrp = hb2 + (size_t)g * 16384;

  // ---- stager mapping (threads 0..255): 32B = records 4*tid .. 4*tid+3 ----
  const int srow = tid >> 7;            // batch row 0..1
  const int sbyte = (tid & 127) * 16;   // LDS byte offset in row

  // ---- A-fragment read addressing (conflict-free: rows split banks) ----
  const int arow = (l15 & 1) * LDSROW;
  const int achunk = (lane >> 4) * 16;

  // ---- zx prologue (1-step-ahead prefetch) ----
  unsigned zprev[4];
  if (tid < 32) {
    const unsigned* zt = (const unsigned*)zx + (size_t)bglob * 2048;
#pragma unroll
    for (int q = 0; q < 4; ++q) zprev[q] = zt[q * 512 + u];
  }

  for (int t = 0; t < T_; ++t) {
    const int par = t & 1;

    // ---- stage: poll own 32B (4 records) until tags >= t; poll IS load ----
    if (tid < 256) {
      const char* src = hgrp + par * 8192 + tid * 32;
      uint4 v0, v1;
      for (;;) {
        ld32_l3_sync(src, v0, v1);   // data valid at return (rule #18 fix)
        if ((int)v0.y >= t && (int)v0.w >= t &&
            (int)v1.y >= t && (int)v1.w >= t) break;
        __builtin_amdgcn_s_sleep(1);
      }
      uint4 hq;
      hq.x = v0.x;
      hq.y = v0.z;
      hq.z = v1.x;
      hq.w = v1.z;
      *reinterpret_cast<uint4*>(lds_h + srow * LDSROW + sbyte) = hq;
    }
    __syncthreads();

    // ---- consume z(t); issue z(t+1) early (HBM latency covered by
    //      MFMA+gate so the next poll's waitcnt is cheap) ----
    unsigned zloc[4];
    if (tid < 32) {
#pragma unroll
      for (int q = 0; q < 4; ++q) zloc[q] = zprev[q];
      int tp = t + 1 < T_ ? t + 1 : t;
      const unsigned* zt = (const unsigned*)zx + (size_t)(tp * 16 + bglob) * 2048;
#pragma unroll
      for (int q = 0; q < 4; ++q) zprev[q] = zt[q * 512 + u];
    }

    // ---- MFMA: 32 k-iters, 4 chains, conflict-free A reads ----
    f32x4 a0 = {0.f, 0.f, 0.f, 0.f};
    f32x4 a1 = {0.f, 0.f, 0.f, 0.f};
    f32x4 a2 = {0.f, 0.f, 0.f, 0.f};
    f32x4 a3 = {0.f, 0.f, 0.f, 0.f};
#pragma unroll
    for (int kk = 0; kk < 32; kk += 4) {
      bf16x8 x0 = *reinterpret_cast<const bf16x8*>(lds_h + arow + (kk + 0) * 64 + achunk);
      bf16x8 x1 = *reinterpret_cast<const bf16x8*>(lds_h + arow + (kk + 1) * 64 + achunk);
      bf16x8 x2 = *reinterpret_cast<const bf16x8*>(lds_h + arow + (kk + 2) * 64 + achunk);
      bf16x8 x3 = *reinterpret_cast<const bf16x8*>(lds_h + arow + (kk + 3) * 64 + achunk);
      a0 = MFMA(x0, uf[kk + 0], a0);
      a1 = MFMA(x1, uf[kk + 1], a1);
      a2 = MFMA(x2, uf[kk + 2], a2);
      a3 = MFMA(x3, uf[kk + 3], a3);
    }
    if (lane < 16) {
      f32x4 s = (a0 + a1) + (a2 + a3);
      zp[0][w * 16 + lane] = s[0];
      zp[1][w * 16 + lane] = s[1];
    }
    __syncthreads();

    // ---- gate + publish {h, tag} (first!) + out store ----
    if (tid < 32) {
      float zr[4], zi[4];
#pragma unroll
      for (int q = 0; q < 4; ++q) {
        zr[q] = zp[gb][q * 16 + gu] + brg[q] +
                bf2f((unsigned short)(zloc[q] & 0xFFFFu));
        zi[q] = zp[gb][64 + q * 16 + gu] + big[q] +
                bf2f((unsigned short)(zloc[q] >> 16));
      }
      float ar = tanh_f(zr[0]), ai = tanh_f(zi[0]);
      float ir = sigm(zr[1]), ii = sigm(zi[1]);
      float fr = sigm(zr[2]), fi = sigm(zi[2]);
      float og_r = sigm(zr[3]), og_i = sigm(zi[3]);
      float ncr = ar * ir - ai * ii + fr * cr - fi * ci;
      float nci = ar * ii + ai * ir + fr * ci + fi * cr;
      cr = ncr;
      ci = nci;
      float tr = tanh_f(cr), ti = tanh_f(ci);
      float hr = og_r * tr - og_i * ti;
      float hi = og_r * ti + og_i * tr;

      i32x2 rec;
      rec.x = (int)((unsigned)f2bf(hr) | ((unsigned)f2bf(hi) << 16));
      rec.y = t + 1;
      st8_l3(hgrp + (par ^ 1) * 8192 + (size_t)(gb * 512 + u) * 8, rec);

      float2 hv;
      hv.x = hr;
      hv.y = hi;
      *reinterpret_cast<float2*>(out + ((size_t)(bglob * T_ + t) * U_ + u) * 2) = hv;
    }
    // no trailing barrier: the tag protocol itself bounds skew to 1 step.
  }
}

// ---------------------------------------------------------------------------
extern "C" void kernel_launch(void* const* d_in, const int* in_sizes, int n_in,
                              void* d_out, int out_size, void* d_ws, size_t ws_size,
                              hipStream_t stream) {
  const float* xr = (const float*)d_in[0];
  const float* xi = (const float*)d_in[1];
  const float* Wr = (const float*)d_in[2];
  const float* Wi = (const float*)d_in[3];
  const float* Ur = (const float*)d_in[4];
  const float* Ui = (const float*)d_in[5];
  const float* br = (const float*)d_in[6];
  const float* bi = (const float*)d_in[7];

  const size_t SZ_ZX = (size_t)M_ * G4 * 2 * 2;   // 262,144,000
  const size_t SZ_AB = (size_t)M_ * KP * 2;       //  65,536,000
  const size_t SZ_BT = (size_t)JP * KP * 2;       //   8,388,608
  const size_t SZ_HB2 = (size_t)NGRP * 16384;     //     131,072
  const size_t OFF_ZX = 0;
  const size_t OFF_AB = OFF_ZX + SZ_ZX;
  const size_t OFF_BW = OFF_AB + SZ_AB;
  const size_t OFF_BU = OFF_BW + SZ_BT;
  const size_t OFF_HB = OFF_BU + SZ_BT;
  const size_t NEEDED = OFF_HB + SZ_HB2;
  if (ws_size < NEEDED) return;  // insufficient scratch

  char* ws = (char*)d_ws;
  unsigned short* zx = (unsigned short*)(ws + OFF_ZX);
  unsigned short* Ab = (unsigned short*)(ws + OFF_AB);
  unsigned short* BtW = (unsigned short*)(ws + OFF_BW);
  unsigned short* BtU = (unsigned short*)(ws + OFF_BU);
  char* hb2 = ws + OFF_HB;

  // zero h0 records {h=0, tag=0}, every launch (graph replay!)
  hipMemsetAsync(ws + OFF_HB, 0, SZ_HB2, stream);

  hipLaunchKernelGGL(k_convert_x, dim3(8000), dim3(256), 0, stream, xr, xi, Ab);
  hipLaunchKernelGGL(k_pack_B, dim3(16384), dim3(256), 0, stream, Wr, Wi, BtW);
  hipLaunchKernelGGL(k_pack_B, dim3(16384), dim3(256), 0, stream, Ur, Ui, BtU);
  hipLaunchKernelGGL(k_gemm_zx, dim3(250 * 32), dim3(256), 0, stream, Ab, BtW, zx);
  hipLaunchKernelGGL(k_scan, dim3(SCAN_BLOCKS), dim3(512), 0, stream, zx, BtU,
                     br, bi, hb2, (float*)d_out);
}